// Round 15
// baseline (372.578 us; speedup 1.0000x reference)
//
#include <hip/hip_runtime.h>
#include <hip/hip_bf16.h>

typedef unsigned short u16;
typedef __bf16 bf16x8 __attribute__((ext_vector_type(8)));
typedef float f32x4 __attribute__((ext_vector_type(4)));
typedef float f32x16 __attribute__((ext_vector_type(16)));
typedef int i32x2 __attribute__((ext_vector_type(2)));

#define PTS_STRIDE (387*4096)

// ---- scratch layout (bytes), no aliasing ----
#define OFF_CONV 0ll
#define OFF_CRDF 9887232ll
#define OFF_WT   9985536ll
#define OFF_NF   13524480ll
#define OFF_QKV  19815936ll
#define OFF_AOP  38690304ll
#define OFF_CAT1 44981760ll
#define OFF_A1   57564672ll
#define OFF_A2   63856128ll
#define OFF_OUT1 70147584ll
#define OFF_OUT2 76439040ll
#define OFF_H1   82730496ll
#define OFF_FIN  95313408ll     // fp32 (unused since R14)
#define OFF_IDX  107896320ll
#define OFF_VT   108158464ll    // V^T bf16 [b*6+h][64][4096]
#define OFF_FT   114449920ll    // features row-major bf16 [b*4096+n][384]
#define OFF_PO   120741376ll    // partial O f32 [ks*12 + b*6+h][4096][64]
#define OFF_PD   145907200ll    // partial denom f32 [ks*12 + b*6+h][4096]
#define WS_NEED  146300416ull

// converted-input element offsets within CONV (u16 elements)
// (points region [0, 3170304) is DEAD since R15: ftrans reads raw input)
#define CV_LN1G 3170304ll
#define CV_LN1B 3170688ll
#define CV_AOB  3760896ll
#define CV_KNNB 4056192ll
#define CV_MRGB 4351488ll
#define CV_LN2G 4351872ll
#define CV_LN2B 4352256ll
#define CV_FF1B 4647552ll
#define CV_FF2B 4943232ll

// transposed-weight element offsets within WT (u16 elements)
#define WT_QKV 0ll
#define WT_AO  442368ll
#define WT_KNN 589824ll
#define WT_MRG 884736ll
#define WT_FF1 1179648ll
#define WT_FF2 1474560ll

static char* g_scratch = nullptr;
__attribute__((constructor)) static void athena_ws_init(void){
  void* p = nullptr;
  if (hipMalloc(&p, WS_NEED) != hipSuccess) p = nullptr;
  g_scratch = (char*)p;
}

static __device__ __forceinline__ float bf2f(u16 u){
  union { unsigned int i; float f; } x; x.i = ((unsigned int)u) << 16; return x.f;
}
static __device__ __forceinline__ u16 f2bf(float f){
  __hip_bfloat16 h = __float2bfloat16(f);
  u16 u; __builtin_memcpy(&u, &h, 2); return u;
}
// pack two f32 -> u32 of 2 bf16 (truncating): low16 = a, high16 = b
static __device__ __forceinline__ unsigned pack2(float a, float b){
  union { float f; unsigned u; } x, y; x.f = a; y.f = b;
  return (x.u >> 16) | (y.u & 0xFFFF0000u);
}
// async global->LDS, 16B per lane; lds dest = wave-uniform base + lane*16
static __device__ __forceinline__ void gload_lds16(const u16* g, u16* l){
  __builtin_amdgcn_global_load_lds(
      (const __attribute__((address_space(1))) unsigned int*)g,
      (__attribute__((address_space(3))) unsigned int*)l, 16, 0, 0);
}

// ---------------- stage0: fused convert + weight-transpose + feature-transpose -------
// All parts depend only on d_in. Block ranges:
//   [0,512)      : 6 weight matrices, raw -> bf16 (+Q-col pre-scale) -> transposed wT
//   [512,1280)   : feature transpose pts(b,3+d,n) raw -> ft[b*4096+n][384] bf16
//   [1280,1284)  : 9 small param arrays raw -> bf16 -> cv sections
//   [1284,1380)  : coords raw -> crd f32 + d_out channels 0..2
struct InPtrs { const void* p[16]; };
__global__ __launch_bounds__(256) void stage0(
    InPtrs ip, u16* __restrict__ cv, u16* __restrict__ wT,
    u16* __restrict__ ft, float* __restrict__ crd, float* __restrict__ out)
{
  __shared__ u16 tile[64*72];
  const bool isbf = (((const u16*)ip.p[1])[0] == 0x3F80);
  const int bid = blockIdx.x;
  if (bid < 512){
    const int widx[6] = {3, 4, 6, 8, 12, 14};
    const long dof[6] = {WT_QKV, WT_AO, WT_KNN, WT_MRG, WT_FF1, WT_FF2};
    const int Rt[6] = {384, 384, 768, 768, 384, 768};
    const int Ct[6] = {1152, 384, 384, 384, 768, 384};
    const int tid = bid*256 + threadIdx.x;
    const int nth = 512*256;
    for (int s = 0; s < 6; ++s){
      const void* src = ip.p[widx[s]];
      u16* outp = wT + dof[s];
      const int R = Rt[s], Cc = Ct[s], total = R*Cc;
      for (int i = tid; i < total; i += nth){
        int r = i / Cc, c = i - r*Cc;
        float f = isbf ? bf2f(((const u16*)src)[i]) : ((const float*)src)[i];
        if (s == 0 && c < 384) f *= 0.18033688f;   // Q pre-scale 1/8*log2e
        outp[(long)c*R + r] = f2bf(f);
      }
    }
  } else if (bid < 1280){
    const int t = threadIdx.x;
    int lb = bid - 512;                    // 0..767
    const int b = lb / 384; lb -= b*384;   // 384 = 64 n-tiles * 6 d-tiles
    const int d0 = (lb / 64) * 64;
    const int n0 = (lb & 63) * 64;
    {
      int dd = t >> 2, nc = (t & 3) * 16;
      const long so = (long)b*PTS_STRIDE + (long)(3+d0+dd)*4096 + n0 + nc;
      union { uint4 v[2]; u16 s[16]; } tv;
      if (isbf){
        const u16* sp = (const u16*)ip.p[0] + so;
        tv.v[0] = *(const uint4*)sp; tv.v[1] = *(const uint4*)(sp+8);
      } else {
        const float* sp = (const float*)ip.p[0] + so;
#pragma unroll
        for (int j = 0; j < 16; ++j) tv.s[j] = f2bf(sp[j]);
      }
#pragma unroll
      for (int j = 0; j < 16; ++j) tile[dd*72 + nc + j] = tv.s[j];
    }
    __syncthreads();
    {
      int nn = t >> 2, dc = (t & 3) * 16;
      union { uint4 v[2]; u16 s[16]; } tw;
#pragma unroll
      for (int j = 0; j < 16; ++j) tw.s[j] = tile[(dc+j)*72 + nn];
      u16* dst = &ft[((long)(b*4096 + n0 + nn))*384 + d0 + dc];
      *(uint4*)dst = tw.v[0]; *(uint4*)(dst+8) = tw.v[1];
    }
  } else if (bid < 1284){
    const int tid = (bid-1280)*256 + threadIdx.x;   // 0..1023
    const int nth = 4*256;
    const int pidx[9] = {1, 2, 5, 7, 9, 10, 11, 13, 15};
    const long coff[9] = {CV_LN1G, CV_LN1B, CV_AOB, CV_KNNB, CV_MRGB,
                          CV_LN2G, CV_LN2B, CV_FF1B, CV_FF2B};
    const int cnt[9] = {384, 384, 384, 384, 384, 384, 384, 768, 384};
    for (int s = 0; s < 9; ++s){
      const void* src = ip.p[pidx[s]];
      for (int i = tid; i < cnt[s]; i += nth){
        u16 v = isbf ? ((const u16*)src)[i] : f2bf(((const float*)src)[i]);
        cv[coff[s] + i] = v;
      }
    }
  } else {
    const int tid = (bid-1284)*256 + threadIdx.x;
    const int nth = 96*256;
    for (int i = tid; i < 24576; i += nth){
      int b = i / 12288, r = i % 12288;
      long off = (long)b*PTS_STRIDE + r;
      float v = isbf ? bf2f(((const u16*)ip.p[0])[off]) : ((const float*)ip.p[0])[off];
      crd[i] = v;
      out[off] = v;
    }
  }
}

// ---------------- V^T pre-transpose: qkv -> vT[(b*6+h)][d][n] ----------------
__global__ __launch_bounds__(256) void vtrans_k(
    const u16* __restrict__ qkv, u16* __restrict__ vT)
{
  __shared__ u16 tile[64*72];
  const int n0 = blockIdx.x*64, h = blockIdx.y, b = blockIdx.z;
  const int t = threadIdx.x;
  {
    int n = n0 + (t & 63), db = (t >> 6) * 16;
    const u16* src = &qkv[((long)b*4096 + n)*1152 + 768 + h*64 + db];
    union { uint4 v[2]; u16 s[16]; } tv;
    tv.v[0] = *(const uint4*)src; tv.v[1] = *(const uint4*)(src+8);
#pragma unroll
    for (int j = 0; j < 16; ++j) tile[(db+j)*72 + (t & 63)] = tv.s[j];
  }
  __syncthreads();
  {
    int d = t >> 2, nc = (t & 3) * 16;
    union { uint4 v[2]; u16 s[16]; } tv;
#pragma unroll
    for (int j = 0; j < 16; ++j) tv.s[j] = tile[d*72 + nc + j];
    u16* dst = &vT[((long)(b*6 + h)*64 + d)*4096 + n0 + nc];
    *(uint4*)dst = tv.v[0]; *(uint4*)(dst+8) = tv.v[1];
  }
}

// ---------------- LayerNorm bf16 (fp32 internal), row-major input ----------------
__global__ __launch_bounds__(256) void ln_kernel(
    const u16* __restrict__ in, const u16* __restrict__ g,
    const u16* __restrict__ bb, u16* __restrict__ out)
{
  const int w = threadIdx.x >> 6, lane = threadIdx.x & 63;
  const int row = blockIdx.x * 4 + w;
  float x[6];
#pragma unroll
  for (int i = 0; i < 6; ++i){
    int d = lane + i*64;
    x[i] = bf2f(in[(long)row*384 + d]);
  }
  float s = 0.f;
#pragma unroll
  for (int i = 0; i < 6; ++i) s += x[i];
#pragma unroll
  for (int off = 1; off < 64; off <<= 1) s += __shfl_xor(s, off);
  float mean = s * (1.f/384.f);
  float vs = 0.f;
#pragma unroll
  for (int i = 0; i < 6; ++i){ float d = x[i]-mean; vs += d*d; }
#pragma unroll
  for (int off = 1; off < 64; off <<= 1) vs += __shfl_xor(vs, off);
  float rstd = 1.f / sqrtf(vs * (1.f/384.f) + 1e-5f);
#pragma unroll
  for (int i = 0; i < 6; ++i){
    int d = lane + i*64;
    out[(long)row*384 + d] = f2bf((x[i]-mean)*rstd*bf2f(g[d]) + bf2f(bb[d]));
  }
}

// ---------------- 64x64-tile bf16 MFMA GEMM body, BK=128 (gload_lds + T2 swizzle) ----
// cf32 modes: 0 = bf16 C; 1 = fp32 C (linear); 2 = fp32 TRANSPOSED direct to
// points-layout out (fused write_out): out[b][3+col][n], float4 over n=quad*4..+3.
static __device__ __forceinline__ void gemm64_body(
    const u16* __restrict__ A, int lda,
    const u16* __restrict__ B, int ldb,
    void* C0, int ldc, int cf32,
    const u16* __restrict__ bias,
    const u16* __restrict__ resid, int ldr,
    int Kd, int act, int m0, int n0,
    u16* As, u16* Bs)
{
  const int tid = threadIdx.x;
  const int wv = tid >> 6, lane = tid & 63, quad = lane >> 4, l16 = lane & 15;
  const int wr = wv >> 1, wc = wv & 1;               // 2x2 wave grid, 32x32 each
  const int r4 = lane >> 4;                           // 0..3 row within a call
  const int sl = lane & 15;                           // 16B slot 0..15

  f32x4 acc[2][2] = { { {0,0,0,0},{0,0,0,0} }, { {0,0,0,0},{0,0,0,0} } };
  const int rsw = l16 * 8;                            // read-side XOR (row&15)*8

  for (int k0 = 0; k0 < Kd; k0 += 128){
    __syncthreads();   // all waves done reading LDS from previous step
#pragma unroll
    for (int c = 0; c < 4; ++c){
      const int rbase = wv*16 + c*4;                  // 4 rows per call
      const int rowin = rbase + r4;
      const int scol = (sl ^ (rowin & 15)) * 8;       // inverse-swizzled global col
      gload_lds16(A + (long)(m0 + rowin)*lda + k0 + scol, &As[rbase*128]);
      gload_lds16(B + (long)(n0 + rowin)*ldb + k0 + scol, &Bs[rbase*128]);
    }
    __syncthreads();   // implicit vmcnt(0) drain: tiles visible
#pragma unroll
    for (int ks2 = 0; ks2 < 4; ++ks2){
      const int rc = (ks2*32 + quad*8) ^ rsw;
      bf16x8 af[2], bfr[2];
#pragma unroll
      for (int mt = 0; mt < 2; ++mt)
        af[mt] = *(const bf16x8*)&As[(wr*32 + mt*16 + l16)*128 + rc];
#pragma unroll
      for (int nt = 0; nt < 2; ++nt)
        bfr[nt] = *(const bf16x8*)&Bs[(wc*32 + nt*16 + l16)*128 + rc];
#pragma unroll
      for (int mt = 0; mt < 2; ++mt)
#pragma unroll
        for (int nt = 0; nt < 2; ++nt)
          acc[mt][nt] = __builtin_amdgcn_mfma_f32_16x16x32_bf16(af[mt], bfr[nt], acc[mt][nt], 0, 0, 0);
    }
  }
#pragma unroll
  for (int nt = 0; nt < 2; ++nt){
    const int col = n0 + wc*32 + nt*16 + l16;
    const float bv = bias ? bf2f(bias[col]) : 0.f;
#pragma unroll
    for (int mt = 0; mt < 2; ++mt){
      if (cf32 == 2){
        // fused transposed store to points layout: row = b*4096+n, col = d
        const int row = m0 + wr*32 + mt*16 + quad*4;   // n base (r = 0..3 consecutive)
        f32x4 vv;
#pragma unroll
        for (int r = 0; r < 4; ++r){
          float v = acc[mt][nt][r] + bv;
          if (resid) v += bf2f(resid[(long)(row + r)*ldr + col]);
          vv[r] = v;
        }
        const long off = (long)(row >> 12)*PTS_STRIDE + (long)(3 + col)*4096 + (row & 4095);
        *(f32x4*)&((float*)C0)[off] = vv;
      } else {
#pragma unroll
        for (int r = 0; r < 4; ++r){
          const int row = m0 + wr*32 + mt*16 + quad*4 + r;  // C/D: row=quad*4+r, col=l16
          float v = acc[mt][nt][r] + bv;
          if (act == 1) v = 0.5f * v * (1.f + erff(v * 0.70710678f));
          if (resid) v += bf2f(resid[(long)row*ldr + col]);
          if (cf32) ((float*)C0)[(long)row*ldc + col] = v;
          else      ((u16*)C0)[(long)row*ldc + col] = f2bf(v);
        }
      }
    }
  }
}

// ---------------- Unified GEMM (64x64 tile, BK=128) ----------------
__global__ __launch_bounds__(256) void gemm_k(
    const u16* __restrict__ A, int lda,
    const u16* __restrict__ B, int ldb,
    void* C0, int ldc, int cf32,
    const u16* __restrict__ bias,
    const u16* __restrict__ resid, int ldr,
    int Kd, int act)
{
  __shared__ u16 As[64*128];
  __shared__ u16 Bs[64*128];
  gemm64_body(A, lda, B, ldb, C0, ldc, cf32, bias, resid, ldr, Kd, act,
              blockIdx.y*64, blockIdx.x*64, As, Bs);
}

// ---------------- grouped GEMM: 3 independent M=8192,N=384,K=384 GEMMs --------------
__global__ __launch_bounds__(256) void gemm3_k(
    const u16* __restrict__ aop, const u16* __restrict__ nf,
    const u16* __restrict__ wTao, const u16* __restrict__ wTknn,
    u16* __restrict__ cat1, u16* __restrict__ A1, u16* __restrict__ A2,
    const u16* __restrict__ aob, const u16* __restrict__ knnb)
{
  __shared__ u16 As[64*128];
  __shared__ u16 Bs[64*128];
  const int z = blockIdx.z;
  const u16* A  = (z == 0) ? aop : nf;
  const u16* B  = (z == 0) ? wTao : (z == 1 ? wTknn : wTknn + 384);
  const int ldb = (z == 0) ? 384 : 768;
  u16* C        = (z == 0) ? cat1 : (z == 1 ? A1 : A2);
  const int ldc = (z == 0) ? 768 : 384;
  const u16* bias = (z == 0) ? aob : (z == 2 ? knnb : nullptr);
  gemm64_body(A, 384, B, ldb, C, ldc, 0, bias, nullptr, 0, 384, 0,
              blockIdx.y*64, blockIdx.x*64, As, Bs);
}

// ---------------- Flash attention v8: 32x32 MFMA, P in-register, K-SPLIT ------------
// grid = (N/128, H, B*2) = 768 blocks (3/CU exact, 12 waves/CU, 3 waves/SIMD).
// blockIdx.z = b*2 + ksplit; each block processes 32 of 64 k-tiles and writes
// UNNORMALIZED partial O (f32) + partial denominator; combine merges.
// Softmax via raw v_exp_f32 (__builtin_amdgcn_exp2f).
__global__ __launch_bounds__(256) void flash_attn(
    const u16* __restrict__ qkv, const u16* __restrict__ vT,
    float* __restrict__ po, float* __restrict__ pd)
{
  __shared__ u16 ks_[2][64*72];   // K tile [k][d]
  __shared__ u16 vs_[2][64*72];   // V^T tile [d][k]
  const int tid = threadIdx.x;
  const int w = tid >> 6, lane = tid & 63;
  const int l31 = lane & 31, hi = lane >> 5;
  const int q0 = blockIdx.x * 128, h = blockIdx.y;
  const int b = blockIdx.z & 1, ks0 = blockIdx.z >> 1;
  const int t0 = ks0 * 32;        // first k-tile of this split
  const long base = (long)b * 4096 * 1152;
  const u16* vrow = vT + (long)(b*6 + h)*262144;

  // Q fragments (B-operand): lane holds q-col = q0+w*32+l31; d = dm*16 + hi*8 + j
  bf16x8 qf[4];
  {
    const long qoff = base + (long)(q0 + w*32 + l31)*1152 + h*64 + hi*8;
#pragma unroll
    for (int dm = 0; dm < 4; ++dm)
      qf[dm] = *(const bf16x8*)&qkv[qoff + dm*16];
  }
  bf16x8 ones;
#pragma unroll
  for (int i = 0; i < 8; ++i) ones[i] = (__bf16)1.0f;

  f32x16 o0 = {}, o1 = {}, dn = {};

  // cooperative staging: rows sr = tid>>2 (0..63), cols sk = (tid&3)*16, 2x uint4 each
  const int sr = tid >> 2, sk = (tid & 3) * 16;
  const u16* kg = qkv + base + 384 + h*64 + (long)sr*1152 + sk;
  const u16* vg = vrow + (long)sr*4096 + sk;

  // prologue: stage tile t0 into buffer 0
  {
    const u16* kg0 = kg + (long)t0*64*1152;
    const u16* vg0 = vg + t0*64;
    uint4 k0 = *(const uint4*)kg0,  k1 = *(const uint4*)(kg0+8);
    uint4 v0 = *(const uint4*)vg0,  v1 = *(const uint4*)(vg0+8);
    *(uint4*)&ks_[0][sr*72+sk] = k0;  *(uint4*)&ks_[0][sr*72+sk+8] = k1;
    *(uint4*)&vs_[0][sr*72+sk] = v0;  *(uint4*)&vs_[0][sr*72+sk+8] = v1;
  }

  for (int kt = 0; kt < 32; ++kt){
    const int cur = kt & 1;
    uint4 k0, k1, v0, v1;
    const bool pre = (kt < 31);
    if (pre){
      const u16* kgn = kg + (long)(t0 + kt + 1)*64*1152;
      const u16* vgn = vg + (t0 + kt + 1)*64;
      k0 = *(const uint4*)kgn; k1 = *(const uint4*)(kgn+8);
      v0 = *(const uint4*)vgn; v1 = *(const uint4*)(vgn+8);
    }
    __syncthreads();   // staged[cur] visible; prev iter's reads of buf[cur^1] done

    // QK^T: two 32x32 S^T tiles (k-halves). z[r] = S[q=l31][k = (r&3)+8*(r>>2)+4*hi]
    bf16x8 pa[4];
#pragma unroll
    for (int t = 0; t < 2; ++t){
      f32x16 z = {};
#pragma unroll
      for (int dm = 0; dm < 4; ++dm){
        bf16x8 kf = *(const bf16x8*)&ks_[cur][(t*32 + l31)*72 + dm*16 + hi*8];
        z = __builtin_amdgcn_mfma_f32_32x32x16_bf16(kf, qf[dm], z, 0, 0, 0);
      }
      float p[16];
#pragma unroll
      for (int r = 0; r < 16; ++r) p[r] = __builtin_amdgcn_exp2f(z[r]);
      // build PV A-fragments for the two 16-k subtiles of this tile:
      // frag word j covers k = {2j,2j+1} (lanes hi=0) / {8+2j,8+2j+1} (hi=1).
      // permlane32_swap(vdst,vsrc): vdst.hi-lanes <-> vsrc.lo-lanes.
#pragma unroll
      for (int s = 0; s < 2; ++s){
        const float* pp = p + s*8;
        unsigned a0 = pack2(pp[0], pp[1]);   // k{0,1}+4hi (local)
        unsigned a1 = pack2(pp[4], pp[5]);   // k{8,9}+4hi
        unsigned b0 = pack2(pp[2], pp[3]);   // k{2,3}+4hi
        unsigned b1 = pack2(pp[6], pp[7]);   // k{10,11}+4hi
        i32x2 rA = __builtin_amdgcn_permlane32_swap((int)a0, (int)a1, false, false);
        i32x2 rB = __builtin_amdgcn_permlane32_swap((int)b0, (int)b1, false, false);
        union { unsigned u[4]; bf16x8 v; } fr;
        fr.u[0] = (unsigned)rA[0];   // k{0,1}/{8,9}
        fr.u[1] = (unsigned)rB[0];   // k{2,3}/{10,11}
        fr.u[2] = (unsigned)rA[1];   // k{4,5}/{12,13}
        fr.u[3] = (unsigned)rB[1];   // k{6,7}/{14,15}
        pa[t*2 + s] = fr.v;
      }
    }

    // write next tile into the other buffer (its readers are past next barrier)
    if (pre){
      *(uint4*)&ks_[cur^1][sr*72+sk] = k0;  *(uint4*)&ks_[cur^1][sr*72+sk+8] = k1;
      *(uint4*)&vs_[cur^1][sr*72+sk] = v0;  *(uint4*)&vs_[cur^1][sr*72+sk+8] = v1;
    }

    // PV + denominator, all on the MFMA pipe. vf: lane col d = dsub*32+l31, k = ks*16+hi*8+j
#pragma unroll
    for (int ks = 0; ks < 4; ++ks){
      bf16x8 vf0 = *(const bf16x8*)&vs_[cur][(l31)*72      + ks*16 + hi*8];
      bf16x8 vf1 = *(const bf16x8*)&vs_[cur][(32 + l31)*72 + ks*16 + hi*8];
      o0 = __builtin_amdgcn_mfma_f32_32x32x16_bf16(pa[ks], vf0, o0, 0, 0, 0);
      o1 = __builtin_amdgcn_mfma_f32_32x32x16_bf16(pa[ks], vf1, o1, 0, 0, 0);
      dn = __builtin_amdgcn_mfma_f32_32x32x16_bf16(pa[ks], ones, dn, 0, 0, 0);
    }
  }

  // write UNNORMALIZED partials. C/D rows: q = (r&3)+8*(r>>2)+4*hi; cols d = dsub*32+l31.
  const long slab = (long)(ks0*12 + b*6 + h) * 4096;
#pragma unroll
  for (int r = 0; r < 16; ++r){
    const int q = (r & 3) + 8*(r >> 2) + 4*hi;
    const long qi = slab + q0 + w*32 + q;
    po[qi*64 + l31]      = o0[r];
    po[qi*64 + 32 + l31] = o1[r];
    if (l31 == 0) pd[qi] = dn[r];
  }
}

// ---------------- fused: attn_combine + KNN top-8 (one dispatch) ----------------
// blocks [0,3072): combine the two K-split halves -> aop bf16.
// blocks [3072,4096): KNN top-8 v3 (chunked LDS staging, 2 rows/wave).
__global__ __launch_bounds__(256) void combine_knn(
    const float* __restrict__ po, const float* __restrict__ pd,
    u16* __restrict__ aop,
    const float* __restrict__ crd, int* __restrict__ idxout)
{
  __shared__ float cs[6144];
  if (blockIdx.x < 3072){
    const int idx = blockIdx.x*256 + threadIdx.x;   // < 786432
    const int d4 = idx & 15;
    const int q  = (idx >> 4) & 4095;
    const int bh = idx >> 16;                        // 0..11
    const long r0 = (long)bh*4096 + q;
    const long r1 = (long)(12 + bh)*4096 + q;
    const float inv = 1.f / (pd[r0] + pd[r1]);
    f32x4 a = *(const f32x4*)&po[r0*64 + d4*4];
    f32x4 c = *(const f32x4*)&po[r1*64 + d4*4];
    const int b = bh / 6, h = bh - 6*b;
    ushort4 w4;
    w4.x = f2bf((a[0] + c[0]) * inv);
    w4.y = f2bf((a[1] + c[1]) * inv);
    w4.z = f2bf((a[2] + c[2]) * inv);
    w4.w = f2bf((a[3] + c[3]) * inv);
    *(ushort4*)&aop[((long)(b*4096 + q))*384 + h*64 + d4*4] = w4;
    return;
  }
  // ---- KNN part ----
  const int w = threadIdx.x >> 6, lane = threadIdx.x & 63;
  const int rb = (blockIdx.x - 3072) * 8;
  const int b = rb >> 12;                 // 4096 % 8 == 0: whole block same batch
  const long pb = (long)b * 12288;

  const int rw = rb + w*2;
  float xn[2], yn[2], zn[2], sqn[2];
#pragma unroll
  for (int q = 0; q < 2; ++q){
    const int n = (rw + q) & 4095;
    xn[q] = crd[pb + n]; yn[q] = crd[pb + 4096 + n]; zn[q] = crd[pb + 8192 + n];
    sqn[q] = __fadd_rn(__fadd_rn(__fmul_rn(xn[q],xn[q]), __fmul_rn(yn[q],yn[q])),
                       __fmul_rn(zn[q],zn[q]));
  }

  float bd[2][8]; int bi[2][8];
#pragma unroll
  for (int q = 0; q < 2; ++q)
#pragma unroll
    for (int j = 0; j < 8; ++j){ bd[q][j] = 3.4e38f; bi[q][j] = 0x7fffffff; }

  for (int c0 = 0; c0 < 4096; c0 += 2048){
    __syncthreads();   // previous chunk's reads complete before overwrite
    for (int i = threadIdx.x; i < 1536; i += 256){
      const int s = i >> 9, e = (i & 511) * 4;
      float4 v4 = *(const float4*)&crd[pb + (long)s*4096 + c0 + e];
      *(float4*)&cs[s*2048 + e] = v4;
    }
    __syncthreads();

    for (int m0 = 0; m0 < 2048; m0 += 64){
      const int ml = m0 + lane;
      const int m = c0 + ml;
      const float xm = cs[ml], ym = cs[2048 + ml], zm = cs[4096 + ml];
      const float sqm = __fadd_rn(__fadd_rn(__fmul_rn(xm,xm), __fmul_rn(ym,ym)),
                                  __fmul_rn(zm,zm));
#pragma unroll
      for (int q = 0; q < 2; ++q){
        const float dot = __fadd_rn(__fadd_rn(__fmul_rn(xn[q],xm), __fmul_rn(yn[q],ym)),
                                    __fmul_rn(zn[q],zm));
        float v = __fadd_rn(__fadd_rn(sqn[q], sqm), __fmul_rn(-2.f, dot));
        int vi = m;
        if (v < bd[q][7]){
#pragma unroll
          for (int j = 0; j < 8; ++j){
            bool c = v < bd[q][j];
            float td = bd[q][j]; int ti = bi[q][j];
            bd[q][j] = c ? v : td;  bi[q][j] = c ? vi : ti;
            v = c ? td : v;         vi = c ? ti : vi;
          }
        }
      }
    }
  }
#pragma unroll
  for (int q = 0; q < 2; ++q){
    const int row = rw + q;
    for (int t = 0; t < 8; ++t){
      float rd = bd[q][0]; int ri = bi[q][0]; int rl = lane;
#pragma unroll
      for (int off = 1; off < 64; off <<= 1){
        float od = __shfl_xor(rd, off); int oi = __shfl_xor(ri, off); int ol = __shfl_xor(rl, off);
        bool take = (od < rd) || (od == rd && oi < ri);
        rd = take ? od : rd; ri = take ? oi : ri; rl = take ? ol : rl;
      }
      if (lane == 0) idxout[row*8 + t] = ri;
      if (lane == rl){
#pragma unroll
        for (int j = 0; j < 7; ++j){ bd[q][j] = bd[q][j+1]; bi[q][j] = bi[q][j+1]; }
        bd[q][7] = 3.4e38f; bi[q][7] = 0x7fffffff;
      }
    }
  }
}

// ---------------- gather-max (bf16) -> cat1 cols 384..767 ----------------
__global__ __launch_bounds__(384) void knn_gather_max(
    const u16* __restrict__ A1, const u16* __restrict__ A2,
    const int* __restrict__ idx, u16* __restrict__ cat1)
{
  const int row = blockIdx.x;
  const int d = threadIdx.x;
  const int b = row >> 12;
  const float bs = bf2f(A2[(long)row*384 + d]) - bf2f(A1[(long)row*384 + d]);
  float mx = -3.4e38f;
#pragma unroll
  for (int k = 0; k < 8; ++k){
    int r = idx[row*8 + k] & 4095;
    float v = bf2f(A1[(long)(b*4096 + r)*384 + d]) + bs;
    v = (v > 0.f) ? v : 0.2f*v;
    mx = fmaxf(mx, v);
  }
  cat1[(long)row*768 + 384 + d] = f2bf(mx);
}

extern "C" void kernel_launch(void* const* d_in, const int* in_sizes, int n_in,
                              void* d_out, int out_size, void* d_ws, size_t ws_size,
                              hipStream_t stream) {
  (void)in_sizes; (void)n_in; (void)out_size; (void)ws_size; (void)d_ws;
  float* out = (float*)d_out;          // output dtype = float32 (verified R9)
  char* ws = g_scratch;

  u16*   cv   = (u16*)(ws + OFF_CONV);
  float* crd  = (float*)(ws + OFF_CRDF);
  u16*   wT   = (u16*)(ws + OFF_WT);
  u16*   nf   = (u16*)(ws + OFF_NF);
  u16*   qkv  = (u16*)(ws + OFF_QKV);
  u16*   aop  = (u16*)(ws + OFF_AOP);
  u16*   cat1 = (u16*)(ws + OFF_CAT1);
  u16*   A1b  = (u16*)(ws + OFF_A1);
  u16*   A2b  = (u16*)(ws + OFF_A2);
  u16*   out1 = (u16*)(ws + OFF_OUT1);
  u16*   out2 = (u16*)(ws + OFF_OUT2);
  u16*   h1   = (u16*)(ws + OFF_H1);
  int*   idxb = (int*)(ws + OFF_IDX);
  u16*   vTb  = (u16*)(ws + OFF_VT);
  u16*   ft   = (u16*)(ws + OFF_FT);
  float* pob  = (float*)(ws + OFF_PO);
  float* pdb  = (float*)(ws + OFF_PD);

  const u16 *c_ln1g = cv+CV_LN1G, *c_ln1b = cv+CV_LN1B,
            *c_aob = cv+CV_AOB, *c_knnb = cv+CV_KNNB, *c_mrgb = cv+CV_MRGB,
            *c_ln2g = cv+CV_LN2G, *c_ln2b = cv+CV_LN2B, *c_ff1b = cv+CV_FF1B,
            *c_ff2b = cv+CV_FF2B;
  u16 *wTq = wT+WT_QKV, *wTao = wT+WT_AO, *wTknn = wT+WT_KNN,
      *wTmrg = wT+WT_MRG, *wTff1 = wT+WT_FF1, *wTff2 = wT+WT_FF2;

  // 0. fused stage0: weights transpose + feature transpose + params + coords
  InPtrs ip; for (int i = 0; i < 16; ++i) ip.p[i] = d_in[i];
  stage0<<<1380, 256, 0, stream>>>(ip, cv, wT, ft, crd, out);

  // 1. LN1 (coalesced row-major) -> nf
  ln_kernel<<<2048, 256, 0, stream>>>(ft, c_ln1g, c_ln1b, nf);
  // 2. qkv = nf @ qkv_w   (Q columns pre-scaled by 1/8*log2e in wTq)
  gemm_k<<<dim3(18,128), 256, 0, stream>>>(nf, 384, wTq, 384,
      qkv, 1152, 0, nullptr, nullptr, 0, 384, 0);
  // 2b. V^T pre-transpose
  vtrans_k<<<dim3(64,6,2), 256, 0, stream>>>(qkv, vTb);
  // 3. flash attention v8 (K-split) -> partials
  flash_attn<<<dim3(32,6,4), 256, 0, stream>>>(qkv, vTb, pob, pdb);
  // 3b+5. fused: combine partials -> aop, and top-8 neighbors
  combine_knn<<<4096, 256, 0, stream>>>(pob, pdb, aop, crd, idxb);
  // 4+6. grouped: attn-out GEMM, A1, A2
  gemm3_k<<<dim3(6,128,3), 256, 0, stream>>>(aop, nf, wTao, wTknn,
      cat1, A1b, A2b, c_aob, c_knnb);
  // 7. geom -> cat1 cols 384..767
  knn_gather_max<<<8192, 384, 0, stream>>>(A1b, A2b, idxb, cat1);
  // 8. out1 = cat1 @ merge_w + merge_b + attn(resid = cat1 cols 0..383)
  gemm_k<<<dim3(6,128), 256, 0, stream>>>(cat1, 768, wTmrg, 768,
      out1, 384, 0, c_mrgb, cat1, 768, 768, 0);
  // 9. LN2
  ln_kernel<<<2048, 256, 0, stream>>>(out1, c_ln2g, c_ln2b, out2);
  // 10. h1 = gelu(out2 @ ff1_w + ff1_b)
  gemm_k<<<dim3(12,128), 256, 0, stream>>>(out2, 384, wTff1, 384,
      h1, 768, 0, c_ff1b, nullptr, 0, 384, 1);
  // 11. out[3+d][n] = (h1 @ ff2_w + ff2_b + out2)^T  -- fused write_out (cf32=2)
  gemm_k<<<dim3(6,128), 256, 0, stream>>>(h1, 768, wTff2, 768,
      out, 0, 2, c_ff2b, out2, 384, 768, 0);
}

// Round 16
// 355.894 us; speedup vs baseline: 1.0469x; 1.0469x over previous
//
#include <hip/hip_runtime.h>
#include <hip/hip_bf16.h>

typedef unsigned short u16;
typedef __bf16 bf16x8 __attribute__((ext_vector_type(8)));
typedef float f32x4 __attribute__((ext_vector_type(4)));
typedef float f32x16 __attribute__((ext_vector_type(16)));
typedef int i32x2 __attribute__((ext_vector_type(2)));

#define PTS_STRIDE (387*4096)

// ---- scratch layout (bytes), no aliasing ----
#define OFF_CONV 0ll
#define OFF_CRDF 9887232ll
#define OFF_WT   9985536ll
#define OFF_NF   13524480ll
#define OFF_QKV  19815936ll
#define OFF_AOP  38690304ll
#define OFF_CAT1 44981760ll
#define OFF_A1   57564672ll
#define OFF_A2   63856128ll
#define OFF_OUT1 70147584ll
#define OFF_OUT2 76439040ll
#define OFF_H1   82730496ll
#define OFF_FIN  95313408ll     // fp32 (unused since R14)
#define OFF_IDX  107896320ll
#define OFF_VT   108158464ll    // V^T bf16 [b*6+h][64][4096]
#define OFF_FT   114449920ll    // features row-major bf16 [b*4096+n][384]
#define OFF_PO   120741376ll    // partial O f32 [ks*12 + b*6+h][4096][64]
#define OFF_PD   145907200ll    // partial denom f32 [ks*12 + b*6+h][4096]
#define WS_NEED  146300416ull

// converted-input element offsets within CONV (u16 elements)
// (points region [0, 3170304) is DEAD since R15: ftrans reads raw input)
#define CV_LN1G 3170304ll
#define CV_LN1B 3170688ll
#define CV_AOB  3760896ll
#define CV_KNNB 4056192ll
#define CV_MRGB 4351488ll
#define CV_LN2G 4351872ll
#define CV_LN2B 4352256ll
#define CV_FF1B 4647552ll
#define CV_FF2B 4943232ll

// transposed-weight element offsets within WT (u16 elements)
#define WT_QKV 0ll
#define WT_AO  442368ll
#define WT_KNN 589824ll
#define WT_MRG 884736ll
#define WT_FF1 1179648ll
#define WT_FF2 1474560ll

static char* g_scratch = nullptr;
__attribute__((constructor)) static void athena_ws_init(void){
  void* p = nullptr;
  if (hipMalloc(&p, WS_NEED) != hipSuccess) p = nullptr;
  g_scratch = (char*)p;
}

static __device__ __forceinline__ float bf2f(u16 u){
  union { unsigned int i; float f; } x; x.i = ((unsigned int)u) << 16; return x.f;
}
static __device__ __forceinline__ u16 f2bf(float f){
  __hip_bfloat16 h = __float2bfloat16(f);
  u16 u; __builtin_memcpy(&u, &h, 2); return u;
}
// pack two f32 -> u32 of 2 bf16 (truncating): low16 = a, high16 = b
static __device__ __forceinline__ unsigned pack2(float a, float b){
  union { float f; unsigned u; } x, y; x.f = a; y.f = b;
  return (x.u >> 16) | (y.u & 0xFFFF0000u);
}
// async global->LDS, 16B per lane; lds dest = wave-uniform base + lane*16
static __device__ __forceinline__ void gload_lds16(const u16* g, u16* l){
  __builtin_amdgcn_global_load_lds(
      (const __attribute__((address_space(1))) unsigned int*)g,
      (__attribute__((address_space(3))) unsigned int*)l, 16, 0, 0);
}

// ---------------- stage0: fused convert + weight-transpose + feature-transpose -------
// All parts depend only on d_in. Block ranges:
//   [0,512)      : 6 weight matrices, raw -> bf16 (+Q-col pre-scale) -> transposed wT
//   [512,1280)   : feature transpose pts(b,3+d,n) raw -> ft[b*4096+n][384] bf16
//   [1280,1284)  : 9 small param arrays raw -> bf16 -> cv sections
//   [1284,1380)  : coords raw -> crd f32 + d_out channels 0..2
struct InPtrs { const void* p[16]; };
__global__ __launch_bounds__(256) void stage0(
    InPtrs ip, u16* __restrict__ cv, u16* __restrict__ wT,
    u16* __restrict__ ft, float* __restrict__ crd, float* __restrict__ out)
{
  __shared__ u16 tile[64*72];
  const bool isbf = (((const u16*)ip.p[1])[0] == 0x3F80);
  const int bid = blockIdx.x;
  if (bid < 512){
    const int widx[6] = {3, 4, 6, 8, 12, 14};
    const long dof[6] = {WT_QKV, WT_AO, WT_KNN, WT_MRG, WT_FF1, WT_FF2};
    const int Rt[6] = {384, 384, 768, 768, 384, 768};
    const int Ct[6] = {1152, 384, 384, 384, 768, 384};
    const int tid = bid*256 + threadIdx.x;
    const int nth = 512*256;
    for (int s = 0; s < 6; ++s){
      const void* src = ip.p[widx[s]];
      u16* outp = wT + dof[s];
      const int R = Rt[s], Cc = Ct[s], total = R*Cc;
      for (int i = tid; i < total; i += nth){
        int r = i / Cc, c = i - r*Cc;
        float f = isbf ? bf2f(((const u16*)src)[i]) : ((const float*)src)[i];
        if (s == 0 && c < 384) f *= 0.18033688f;   // Q pre-scale 1/8*log2e
        outp[(long)c*R + r] = f2bf(f);
      }
    }
  } else if (bid < 1280){
    const int t = threadIdx.x;
    int lb = bid - 512;                    // 0..767
    const int b = lb / 384; lb -= b*384;   // 384 = 64 n-tiles * 6 d-tiles
    const int d0 = (lb / 64) * 64;
    const int n0 = (lb & 63) * 64;
    {
      int dd = t >> 2, nc = (t & 3) * 16;
      const long so = (long)b*PTS_STRIDE + (long)(3+d0+dd)*4096 + n0 + nc;
      union { uint4 v[2]; u16 s[16]; } tv;
      if (isbf){
        const u16* sp = (const u16*)ip.p[0] + so;
        tv.v[0] = *(const uint4*)sp; tv.v[1] = *(const uint4*)(sp+8);
      } else {
        const float* sp = (const float*)ip.p[0] + so;
#pragma unroll
        for (int j = 0; j < 16; ++j) tv.s[j] = f2bf(sp[j]);
      }
#pragma unroll
      for (int j = 0; j < 16; ++j) tile[dd*72 + nc + j] = tv.s[j];
    }
    __syncthreads();
    {
      int nn = t >> 2, dc = (t & 3) * 16;
      union { uint4 v[2]; u16 s[16]; } tw;
#pragma unroll
      for (int j = 0; j < 16; ++j) tw.s[j] = tile[(dc+j)*72 + nn];
      u16* dst = &ft[((long)(b*4096 + n0 + nn))*384 + d0 + dc];
      *(uint4*)dst = tw.v[0]; *(uint4*)(dst+8) = tw.v[1];
    }
  } else if (bid < 1284){
    const int tid = (bid-1280)*256 + threadIdx.x;   // 0..1023
    const int nth = 4*256;
    const int pidx[9] = {1, 2, 5, 7, 9, 10, 11, 13, 15};
    const long coff[9] = {CV_LN1G, CV_LN1B, CV_AOB, CV_KNNB, CV_MRGB,
                          CV_LN2G, CV_LN2B, CV_FF1B, CV_FF2B};
    const int cnt[9] = {384, 384, 384, 384, 384, 384, 384, 768, 384};
    for (int s = 0; s < 9; ++s){
      const void* src = ip.p[pidx[s]];
      for (int i = tid; i < cnt[s]; i += nth){
        u16 v = isbf ? ((const u16*)src)[i] : f2bf(((const float*)src)[i]);
        cv[coff[s] + i] = v;
      }
    }
  } else {
    const int tid = (bid-1284)*256 + threadIdx.x;
    const int nth = 96*256;
    for (int i = tid; i < 24576; i += nth){
      int b = i / 12288, r = i % 12288;
      long off = (long)b*PTS_STRIDE + r;
      float v = isbf ? bf2f(((const u16*)ip.p[0])[off]) : ((const float*)ip.p[0])[off];
      crd[i] = v;
      out[off] = v;
    }
  }
}

// ---------------- V^T pre-transpose: qkv -> vT[(b*6+h)][d][n] ----------------
__global__ __launch_bounds__(256) void vtrans_k(
    const u16* __restrict__ qkv, u16* __restrict__ vT)
{
  __shared__ u16 tile[64*72];
  const int n0 = blockIdx.x*64, h = blockIdx.y, b = blockIdx.z;
  const int t = threadIdx.x;
  {
    int n = n0 + (t & 63), db = (t >> 6) * 16;
    const u16* src = &qkv[((long)b*4096 + n)*1152 + 768 + h*64 + db];
    union { uint4 v[2]; u16 s[16]; } tv;
    tv.v[0] = *(const uint4*)src; tv.v[1] = *(const uint4*)(src+8);
#pragma unroll
    for (int j = 0; j < 16; ++j) tile[(db+j)*72 + (t & 63)] = tv.s[j];
  }
  __syncthreads();
  {
    int d = t >> 2, nc = (t & 3) * 16;
    union { uint4 v[2]; u16 s[16]; } tv;
#pragma unroll
    for (int j = 0; j < 16; ++j) tv.s[j] = tile[d*72 + nc + j];
    u16* dst = &vT[((long)(b*6 + h)*64 + d)*4096 + n0 + nc];
    *(uint4*)dst = tv.v[0]; *(uint4*)(dst+8) = tv.v[1];
  }
}

// ---------------- LayerNorm bf16 (fp32 internal), row-major input ----------------
__global__ __launch_bounds__(256) void ln_kernel(
    const u16* __restrict__ in, const u16* __restrict__ g,
    const u16* __restrict__ bb, u16* __restrict__ out)
{
  const int w = threadIdx.x >> 6, lane = threadIdx.x & 63;
  const int row = blockIdx.x * 4 + w;
  float x[6];
#pragma unroll
  for (int i = 0; i < 6; ++i){
    int d = lane + i*64;
    x[i] = bf2f(in[(long)row*384 + d]);
  }
  float s = 0.f;
#pragma unroll
  for (int i = 0; i < 6; ++i) s += x[i];
#pragma unroll
  for (int off = 1; off < 64; off <<= 1) s += __shfl_xor(s, off);
  float mean = s * (1.f/384.f);
  float vs = 0.f;
#pragma unroll
  for (int i = 0; i < 6; ++i){ float d = x[i]-mean; vs += d*d; }
#pragma unroll
  for (int off = 1; off < 64; off <<= 1) vs += __shfl_xor(vs, off);
  float rstd = 1.f / sqrtf(vs * (1.f/384.f) + 1e-5f);
#pragma unroll
  for (int i = 0; i < 6; ++i){
    int d = lane + i*64;
    out[(long)row*384 + d] = f2bf((x[i]-mean)*rstd*bf2f(g[d]) + bf2f(bb[d]));
  }
}

// ---------------- 64x64-tile bf16 MFMA GEMM body, BK=128 (gload_lds + T2 swizzle) ----
// cf32 modes: 0 = bf16 C; 1 = fp32 C (linear); 2 = fp32 TRANSPOSED direct to
// points-layout out (fused write_out): out[b][3+col][n], float4 over n=quad*4..+3.
static __device__ __forceinline__ void gemm64_body(
    const u16* __restrict__ A, int lda,
    const u16* __restrict__ B, int ldb,
    void* C0, int ldc, int cf32,
    const u16* __restrict__ bias,
    const u16* __restrict__ resid, int ldr,
    int Kd, int act, int m0, int n0,
    u16* As, u16* Bs)
{
  const int tid = threadIdx.x;
  const int wv = tid >> 6, lane = tid & 63, quad = lane >> 4, l16 = lane & 15;
  const int wr = wv >> 1, wc = wv & 1;               // 2x2 wave grid, 32x32 each
  const int r4 = lane >> 4;                           // 0..3 row within a call
  const int sl = lane & 15;                           // 16B slot 0..15

  f32x4 acc[2][2] = { { {0,0,0,0},{0,0,0,0} }, { {0,0,0,0},{0,0,0,0} } };
  const int rsw = l16 * 8;                            // read-side XOR (row&15)*8

  for (int k0 = 0; k0 < Kd; k0 += 128){
    __syncthreads();   // all waves done reading LDS from previous step
#pragma unroll
    for (int c = 0; c < 4; ++c){
      const int rbase = wv*16 + c*4;                  // 4 rows per call
      const int rowin = rbase + r4;
      const int scol = (sl ^ (rowin & 15)) * 8;       // inverse-swizzled global col
      gload_lds16(A + (long)(m0 + rowin)*lda + k0 + scol, &As[rbase*128]);
      gload_lds16(B + (long)(n0 + rowin)*ldb + k0 + scol, &Bs[rbase*128]);
    }
    __syncthreads();   // implicit vmcnt(0) drain: tiles visible
#pragma unroll
    for (int ks2 = 0; ks2 < 4; ++ks2){
      const int rc = (ks2*32 + quad*8) ^ rsw;
      bf16x8 af[2], bfr[2];
#pragma unroll
      for (int mt = 0; mt < 2; ++mt)
        af[mt] = *(const bf16x8*)&As[(wr*32 + mt*16 + l16)*128 + rc];
#pragma unroll
      for (int nt = 0; nt < 2; ++nt)
        bfr[nt] = *(const bf16x8*)&Bs[(wc*32 + nt*16 + l16)*128 + rc];
#pragma unroll
      for (int mt = 0; mt < 2; ++mt)
#pragma unroll
        for (int nt = 0; nt < 2; ++nt)
          acc[mt][nt] = __builtin_amdgcn_mfma_f32_16x16x32_bf16(af[mt], bfr[nt], acc[mt][nt], 0, 0, 0);
    }
  }
#pragma unroll
  for (int nt = 0; nt < 2; ++nt){
    const int col = n0 + wc*32 + nt*16 + l16;
    const float bv = bias ? bf2f(bias[col]) : 0.f;
#pragma unroll
    for (int mt = 0; mt < 2; ++mt){
      if (cf32 == 2){
        // fused transposed store to points layout: row = b*4096+n, col = d
        const int row = m0 + wr*32 + mt*16 + quad*4;   // n base (r = 0..3 consecutive)
        f32x4 vv;
#pragma unroll
        for (int r = 0; r < 4; ++r){
          float v = acc[mt][nt][r] + bv;
          if (resid) v += bf2f(resid[(long)(row + r)*ldr + col]);
          vv[r] = v;
        }
        const long off = (long)(row >> 12)*PTS_STRIDE + (long)(3 + col)*4096 + (row & 4095);
        *(f32x4*)&((float*)C0)[off] = vv;
      } else {
#pragma unroll
        for (int r = 0; r < 4; ++r){
          const int row = m0 + wr*32 + mt*16 + quad*4 + r;  // C/D: row=quad*4+r, col=l16
          float v = acc[mt][nt][r] + bv;
          if (act == 1) v = 0.5f * v * (1.f + erff(v * 0.70710678f));
          if (resid) v += bf2f(resid[(long)row*ldr + col]);
          if (cf32) ((float*)C0)[(long)row*ldc + col] = v;
          else      ((u16*)C0)[(long)row*ldc + col] = f2bf(v);
        }
      }
    }
  }
}

// ---------------- Unified GEMM (64x64 tile, BK=128) ----------------
__global__ __launch_bounds__(256) void gemm_k(
    const u16* __restrict__ A, int lda,
    const u16* __restrict__ B, int ldb,
    void* C0, int ldc, int cf32,
    const u16* __restrict__ bias,
    const u16* __restrict__ resid, int ldr,
    int Kd, int act)
{
  __shared__ u16 As[64*128];
  __shared__ u16 Bs[64*128];
  gemm64_body(A, lda, B, ldb, C0, ldc, cf32, bias, resid, ldr, Kd, act,
              blockIdx.y*64, blockIdx.x*64, As, Bs);
}

// ---------------- grouped GEMM: 3 independent M=8192,N=384,K=384 GEMMs --------------
__global__ __launch_bounds__(256) void gemm3_k(
    const u16* __restrict__ aop, const u16* __restrict__ nf,
    const u16* __restrict__ wTao, const u16* __restrict__ wTknn,
    u16* __restrict__ cat1, u16* __restrict__ A1, u16* __restrict__ A2,
    const u16* __restrict__ aob, const u16* __restrict__ knnb)
{
  __shared__ u16 As[64*128];
  __shared__ u16 Bs[64*128];
  const int z = blockIdx.z;
  const u16* A  = (z == 0) ? aop : nf;
  const u16* B  = (z == 0) ? wTao : (z == 1 ? wTknn : wTknn + 384);
  const int ldb = (z == 0) ? 384 : 768;
  u16* C        = (z == 0) ? cat1 : (z == 1 ? A1 : A2);
  const int ldc = (z == 0) ? 768 : 384;
  const u16* bias = (z == 0) ? aob : (z == 2 ? knnb : nullptr);
  gemm64_body(A, 384, B, ldb, C, ldc, 0, bias, nullptr, 0, 384, 0,
              blockIdx.y*64, blockIdx.x*64, As, Bs);
}

// ---------------- Flash attention v8: 32x32 MFMA, P in-register, K-SPLIT ------------
// grid = (N/128, H, B*2) = 768 blocks (3/CU exact, 12 waves/CU, 3 waves/SIMD).
// blockIdx.z = b*2 + ksplit; each block processes 32 of 64 k-tiles and writes
// UNNORMALIZED partial O (f32) + partial denominator; attn_combine merges.
// Softmax via raw v_exp_f32 (__builtin_amdgcn_exp2f).
__global__ __launch_bounds__(256) void flash_attn(
    const u16* __restrict__ qkv, const u16* __restrict__ vT,
    float* __restrict__ po, float* __restrict__ pd)
{
  __shared__ u16 ks_[2][64*72];   // K tile [k][d]
  __shared__ u16 vs_[2][64*72];   // V^T tile [d][k]
  const int tid = threadIdx.x;
  const int w = tid >> 6, lane = tid & 63;
  const int l31 = lane & 31, hi = lane >> 5;
  const int q0 = blockIdx.x * 128, h = blockIdx.y;
  const int b = blockIdx.z & 1, ks0 = blockIdx.z >> 1;
  const int t0 = ks0 * 32;        // first k-tile of this split
  const long base = (long)b * 4096 * 1152;
  const u16* vrow = vT + (long)(b*6 + h)*262144;

  // Q fragments (B-operand): lane holds q-col = q0+w*32+l31; d = dm*16 + hi*8 + j
  bf16x8 qf[4];
  {
    const long qoff = base + (long)(q0 + w*32 + l31)*1152 + h*64 + hi*8;
#pragma unroll
    for (int dm = 0; dm < 4; ++dm)
      qf[dm] = *(const bf16x8*)&qkv[qoff + dm*16];
  }
  bf16x8 ones;
#pragma unroll
  for (int i = 0; i < 8; ++i) ones[i] = (__bf16)1.0f;

  f32x16 o0 = {}, o1 = {}, dn = {};

  // cooperative staging: rows sr = tid>>2 (0..63), cols sk = (tid&3)*16, 2x uint4 each
  const int sr = tid >> 2, sk = (tid & 3) * 16;
  const u16* kg = qkv + base + 384 + h*64 + (long)sr*1152 + sk;
  const u16* vg = vrow + (long)sr*4096 + sk;

  // prologue: stage tile t0 into buffer 0
  {
    const u16* kg0 = kg + (long)t0*64*1152;
    const u16* vg0 = vg + t0*64;
    uint4 k0 = *(const uint4*)kg0,  k1 = *(const uint4*)(kg0+8);
    uint4 v0 = *(const uint4*)vg0,  v1 = *(const uint4*)(vg0+8);
    *(uint4*)&ks_[0][sr*72+sk] = k0;  *(uint4*)&ks_[0][sr*72+sk+8] = k1;
    *(uint4*)&vs_[0][sr*72+sk] = v0;  *(uint4*)&vs_[0][sr*72+sk+8] = v1;
  }

  for (int kt = 0; kt < 32; ++kt){
    const int cur = kt & 1;
    uint4 k0, k1, v0, v1;
    const bool pre = (kt < 31);
    if (pre){
      const u16* kgn = kg + (long)(t0 + kt + 1)*64*1152;
      const u16* vgn = vg + (t0 + kt + 1)*64;
      k0 = *(const uint4*)kgn; k1 = *(const uint4*)(kgn+8);
      v0 = *(const uint4*)vgn; v1 = *(const uint4*)(vgn+8);
    }
    __syncthreads();   // staged[cur] visible; prev iter's reads of buf[cur^1] done

    // QK^T: two 32x32 S^T tiles (k-halves). z[r] = S[q=l31][k = (r&3)+8*(r>>2)+4*hi]
    bf16x8 pa[4];
#pragma unroll
    for (int t = 0; t < 2; ++t){
      f32x16 z = {};
#pragma unroll
      for (int dm = 0; dm < 4; ++dm){
        bf16x8 kf = *(const bf16x8*)&ks_[cur][(t*32 + l31)*72 + dm*16 + hi*8];
        z = __builtin_amdgcn_mfma_f32_32x32x16_bf16(kf, qf[dm], z, 0, 0, 0);
      }
      float p[16];
#pragma unroll
      for (int r = 0; r < 16; ++r) p[r] = __builtin_amdgcn_exp2f(z[r]);
      // build PV A-fragments for the two 16-k subtiles of this tile:
      // frag word j covers k = {2j,2j+1} (lanes hi=0) / {8+2j,8+2j+1} (hi=1).
      // permlane32_swap(vdst,vsrc): vdst.hi-lanes <-> vsrc.lo-lanes.
#pragma unroll
      for (int s = 0; s < 2; ++s){
        const float* pp = p + s*8;
        unsigned a0 = pack2(pp[0], pp[1]);   // k{0,1}+4hi (local)
        unsigned a1 = pack2(pp[4], pp[5]);   // k{8,9}+4hi
        unsigned b0 = pack2(pp[2], pp[3]);   // k{2,3}+4hi
        unsigned b1 = pack2(pp[6], pp[7]);   // k{10,11}+4hi
        i32x2 rA = __builtin_amdgcn_permlane32_swap((int)a0, (int)a1, false, false);
        i32x2 rB = __builtin_amdgcn_permlane32_swap((int)b0, (int)b1, false, false);
        union { unsigned u[4]; bf16x8 v; } fr;
        fr.u[0] = (unsigned)rA[0];   // k{0,1}/{8,9}
        fr.u[1] = (unsigned)rB[0];   // k{2,3}/{10,11}
        fr.u[2] = (unsigned)rA[1];   // k{4,5}/{12,13}
        fr.u[3] = (unsigned)rB[1];   // k{6,7}/{14,15}
        pa[t*2 + s] = fr.v;
      }
    }

    // write next tile into the other buffer (its readers are past next barrier)
    if (pre){
      *(uint4*)&ks_[cur^1][sr*72+sk] = k0;  *(uint4*)&ks_[cur^1][sr*72+sk+8] = k1;
      *(uint4*)&vs_[cur^1][sr*72+sk] = v0;  *(uint4*)&vs_[cur^1][sr*72+sk+8] = v1;
    }

    // PV + denominator, all on the MFMA pipe. vf: lane col d = dsub*32+l31, k = ks*16+hi*8+j
#pragma unroll
    for (int ks = 0; ks < 4; ++ks){
      bf16x8 vf0 = *(const bf16x8*)&vs_[cur][(l31)*72      + ks*16 + hi*8];
      bf16x8 vf1 = *(const bf16x8*)&vs_[cur][(32 + l31)*72 + ks*16 + hi*8];
      o0 = __builtin_amdgcn_mfma_f32_32x32x16_bf16(pa[ks], vf0, o0, 0, 0, 0);
      o1 = __builtin_amdgcn_mfma_f32_32x32x16_bf16(pa[ks], vf1, o1, 0, 0, 0);
      dn = __builtin_amdgcn_mfma_f32_32x32x16_bf16(pa[ks], ones, dn, 0, 0, 0);
    }
  }

  // write UNNORMALIZED partials. C/D rows: q = (r&3)+8*(r>>2)+4*hi; cols d = dsub*32+l31.
  const long slab = (long)(ks0*12 + b*6 + h) * 4096;
#pragma unroll
  for (int r = 0; r < 16; ++r){
    const int q = (r & 3) + 8*(r >> 2) + 4*hi;
    const long qi = slab + q0 + w*32 + q;
    po[qi*64 + l31]      = o0[r];
    po[qi*64 + 32 + l31] = o1[r];
    if (l31 == 0) pd[qi] = dn[r];
  }
}

// ---------------- combine the two K-split halves -> aop bf16 ----------------
// idx = ((b*6+h)*4096 + q)*16 + d4 ; each thread merges 4 consecutive d.
__global__ __launch_bounds__(256) void attn_combine(
    const float* __restrict__ po, const float* __restrict__ pd,
    u16* __restrict__ aop)
{
  const int idx = blockIdx.x*256 + threadIdx.x;   // < 786432
  const int d4 = idx & 15;
  const int q  = (idx >> 4) & 4095;
  const int bh = idx >> 16;                        // 0..11
  const long r0 = (long)bh*4096 + q;
  const long r1 = (long)(12 + bh)*4096 + q;
  const float inv = 1.f / (pd[r0] + pd[r1]);
  f32x4 a = *(const f32x4*)&po[r0*64 + d4*4];
  f32x4 c = *(const f32x4*)&po[r1*64 + d4*4];
  const int b = bh / 6, h = bh - 6*b;
  ushort4 w4;
  w4.x = f2bf((a[0] + c[0]) * inv);
  w4.y = f2bf((a[1] + c[1]) * inv);
  w4.z = f2bf((a[2] + c[2]) * inv);
  w4.w = f2bf((a[3] + c[3]) * inv);
  *(ushort4*)&aop[((long)(b*4096 + q))*384 + h*64 + d4*4] = w4;
}

// ---------------- KNN top-8 v3: chunked LDS staging, 2 rows/wave ----------------
// grid = 1024 blocks x 256 threads; block handles 8 consecutive rows (same batch).
// Candidates processed in 2 chunks of 2048 (LDS 24 KB); query top-8 state in
// registers across chunks. Per-lane insert strict-< only (exact, R12-verified);
// cross-lane merge keeps (dist,idx) tie-break.
__global__ __launch_bounds__(256) void knn_topk(
    const float* __restrict__ crd, int* __restrict__ idxout)
{
  __shared__ float cs[6144];   // [3][2048] per chunk
  const int w = threadIdx.x >> 6, lane = threadIdx.x & 63;
  const int rb = blockIdx.x * 8;
  const int b = rb >> 12;                 // 4096 % 8 == 0: whole block same batch
  const long pb = (long)b * 12288;

  const int rw = rb + w*2;
  float xn[2], yn[2], zn[2], sqn[2];
#pragma unroll
  for (int q = 0; q < 2; ++q){
    const int n = (rw + q) & 4095;
    xn[q] = crd[pb + n]; yn[q] = crd[pb + 4096 + n]; zn[q] = crd[pb + 8192 + n];
    sqn[q] = __fadd_rn(__fadd_rn(__fmul_rn(xn[q],xn[q]), __fmul_rn(yn[q],yn[q])),
                       __fmul_rn(zn[q],zn[q]));
  }

  float bd[2][8]; int bi[2][8];
#pragma unroll
  for (int q = 0; q < 2; ++q)
#pragma unroll
    for (int j = 0; j < 8; ++j){ bd[q][j] = 3.4e38f; bi[q][j] = 0x7fffffff; }

  for (int c0 = 0; c0 < 4096; c0 += 2048){
    __syncthreads();   // previous chunk's reads complete before overwrite
    for (int i = threadIdx.x; i < 1536; i += 256){
      const int s = i >> 9, e = (i & 511) * 4;
      float4 v4 = *(const float4*)&crd[pb + (long)s*4096 + c0 + e];
      *(float4*)&cs[s*2048 + e] = v4;
    }
    __syncthreads();

    for (int m0 = 0; m0 < 2048; m0 += 64){
      const int ml = m0 + lane;
      const int m = c0 + ml;
      const float xm = cs[ml], ym = cs[2048 + ml], zm = cs[4096 + ml];
      const float sqm = __fadd_rn(__fadd_rn(__fmul_rn(xm,xm), __fmul_rn(ym,ym)),
                                  __fmul_rn(zm,zm));
#pragma unroll
      for (int q = 0; q < 2; ++q){
        const float dot = __fadd_rn(__fadd_rn(__fmul_rn(xn[q],xm), __fmul_rn(yn[q],ym)),
                                    __fmul_rn(zn[q],zm));
        float v = __fadd_rn(__fadd_rn(sqn[q], sqm), __fmul_rn(-2.f, dot));
        int vi = m;
        if (v < bd[q][7]){
#pragma unroll
          for (int j = 0; j < 8; ++j){
            bool c = v < bd[q][j];
            float td = bd[q][j]; int ti = bi[q][j];
            bd[q][j] = c ? v : td;  bi[q][j] = c ? vi : ti;
            v = c ? td : v;         vi = c ? ti : vi;
          }
        }
      }
    }
  }
#pragma unroll
  for (int q = 0; q < 2; ++q){
    const int row = rw + q;
    for (int t = 0; t < 8; ++t){
      float rd = bd[q][0]; int ri = bi[q][0]; int rl = lane;
#pragma unroll
      for (int off = 1; off < 64; off <<= 1){
        float od = __shfl_xor(rd, off); int oi = __shfl_xor(ri, off); int ol = __shfl_xor(rl, off);
        bool take = (od < rd) || (od == rd && oi < ri);
        rd = take ? od : rd; ri = take ? oi : ri; rl = take ? ol : rl;
      }
      if (lane == 0) idxout[row*8 + t] = ri;
      if (lane == rl){
#pragma unroll
        for (int j = 0; j < 7; ++j){ bd[q][j] = bd[q][j+1]; bi[q][j] = bi[q][j+1]; }
        bd[q][7] = 3.4e38f; bi[q][7] = 0x7fffffff;
      }
    }
  }
}

// ---------------- gather-max (bf16) -> cat1 cols 384..767 ----------------
__global__ __launch_bounds__(384) void knn_gather_max(
    const u16* __restrict__ A1, const u16* __restrict__ A2,
    const int* __restrict__ idx, u16* __restrict__ cat1)
{
  const int row = blockIdx.x;
  const int d = threadIdx.x;
  const int b = row >> 12;
  const float bs = bf2f(A2[(long)row*384 + d]) - bf2f(A1[(long)row*384 + d]);
  float mx = -3.4e38f;
#pragma unroll
  for (int k = 0; k < 8; ++k){
    int r = idx[row*8 + k] & 4095;
    float v = bf2f(A1[(long)(b*4096 + r)*384 + d]) + bs;
    v = (v > 0.f) ? v : 0.2f*v;
    mx = fmaxf(mx, v);
  }
  cat1[(long)row*768 + 384 + d] = f2bf(mx);
}

extern "C" void kernel_launch(void* const* d_in, const int* in_sizes, int n_in,
                              void* d_out, int out_size, void* d_ws, size_t ws_size,
                              hipStream_t stream) {
  (void)in_sizes; (void)n_in; (void)out_size; (void)ws_size; (void)d_ws;
  float* out = (float*)d_out;          // output dtype = float32 (verified R9)
  char* ws = g_scratch;

  u16*   cv   = (u16*)(ws + OFF_CONV);
  float* crd  = (float*)(ws + OFF_CRDF);
  u16*   wT   = (u16*)(ws + OFF_WT);
  u16*   nf   = (u16*)(ws + OFF_NF);
  u16*   qkv  = (u16*)(ws + OFF_QKV);
  u16*   aop  = (u16*)(ws + OFF_AOP);
  u16*   cat1 = (u16*)(ws + OFF_CAT1);
  u16*   A1b  = (u16*)(ws + OFF_A1);
  u16*   A2b  = (u16*)(ws + OFF_A2);
  u16*   out1 = (u16*)(ws + OFF_OUT1);
  u16*   out2 = (u16*)(ws + OFF_OUT2);
  u16*   h1   = (u16*)(ws + OFF_H1);
  int*   idxb = (int*)(ws + OFF_IDX);
  u16*   vTb  = (u16*)(ws + OFF_VT);
  u16*   ft   = (u16*)(ws + OFF_FT);
  float* pob  = (float*)(ws + OFF_PO);
  float* pdb  = (float*)(ws + OFF_PD);

  const u16 *c_ln1g = cv+CV_LN1G, *c_ln1b = cv+CV_LN1B,
            *c_aob = cv+CV_AOB, *c_knnb = cv+CV_KNNB, *c_mrgb = cv+CV_MRGB,
            *c_ln2g = cv+CV_LN2G, *c_ln2b = cv+CV_LN2B, *c_ff1b = cv+CV_FF1B,
            *c_ff2b = cv+CV_FF2B;
  u16 *wTq = wT+WT_QKV, *wTao = wT+WT_AO, *wTknn = wT+WT_KNN,
      *wTmrg = wT+WT_MRG, *wTff1 = wT+WT_FF1, *wTff2 = wT+WT_FF2;

  // 0. fused stage0: weights transpose + feature transpose + params + coords
  InPtrs ip; for (int i = 0; i < 16; ++i) ip.p[i] = d_in[i];
  stage0<<<1380, 256, 0, stream>>>(ip, cv, wT, ft, crd, out);

  // 1. LN1 (coalesced row-major) -> nf
  ln_kernel<<<2048, 256, 0, stream>>>(ft, c_ln1g, c_ln1b, nf);
  // 2. qkv = nf @ qkv_w   (Q columns pre-scaled by 1/8*log2e in wTq)
  gemm_k<<<dim3(18,128), 256, 0, stream>>>(nf, 384, wTq, 384,
      qkv, 1152, 0, nullptr, nullptr, 0, 384, 0);
  // 2b. V^T pre-transpose
  vtrans_k<<<dim3(64,6,2), 256, 0, stream>>>(qkv, vTb);
  // 3. flash attention v8 (K-split) -> partials -> combine -> aop
  flash_attn<<<dim3(32,6,4), 256, 0, stream>>>(qkv, vTb, pob, pdb);
  attn_combine<<<3072, 256, 0, stream>>>(pob, pdb, aop);
  // 4+6. grouped: attn-out GEMM, A1, A2
  gemm3_k<<<dim3(6,128,3), 256, 0, stream>>>(aop, nf, wTao, wTknn,
      cat1, A1b, A2b, c_aob, c_knnb);
  // 5. top-8 neighbors (chunked LDS, 2 rows/wave)
  knn_topk<<<1024, 256, 0, stream>>>(crd, idxb);
  // 7. geom -> cat1 cols 384..767
  knn_gather_max<<<8192, 384, 0, stream>>>(A1b, A2b, idxb, cat1);
  // 8. out1 = cat1 @ merge_w + merge_b + attn(resid = cat1 cols 0..383)
  gemm_k<<<dim3(6,128), 256, 0, stream>>>(cat1, 768, wTmrg, 768,
      out1, 384, 0, c_mrgb, cat1, 768, 768, 0);
  // 9. LN2
  ln_kernel<<<2048, 256, 0, stream>>>(out1, c_ln2g, c_ln2b, out2);
  // 10. h1 = gelu(out2 @ ff1_w + ff1_b)
  gemm_k<<<dim3(12,128), 256, 0, stream>>>(out2, 384, wTff1, 384,
      h1, 768, 0, c_ff1b, nullptr, 0, 384, 1);
  // 11. out[3+d][n] = (h1 @ ff2_w + ff2_b + out2)^T  -- fused write_out (cf32=2)
  gemm_k<<<dim3(6,128), 256, 0, stream>>>(h1, 768, wTff2, 768,
      out, 0, 2, c_ff2b, out2, 384, 768, 0);
}

// Round 17
// 350.397 us; speedup vs baseline: 1.0633x; 1.0157x over previous
//
#include <hip/hip_runtime.h>
#include <hip/hip_bf16.h>

typedef unsigned short u16;
typedef __bf16 bf16x8 __attribute__((ext_vector_type(8)));
typedef float f32x4 __attribute__((ext_vector_type(4)));
typedef float f32x16 __attribute__((ext_vector_type(16)));
typedef int i32x2 __attribute__((ext_vector_type(2)));

#define PTS_STRIDE (387*4096)

// ---- scratch layout (bytes), no aliasing ----
#define OFF_CONV 0ll
#define OFF_CRDF 9887232ll
#define OFF_WT   9985536ll
#define OFF_NF   13524480ll
#define OFF_QKV  19815936ll
#define OFF_AOP  38690304ll
#define OFF_CAT1 44981760ll
#define OFF_A1   57564672ll
#define OFF_A2   63856128ll
#define OFF_OUT1 70147584ll
#define OFF_OUT2 76439040ll
#define OFF_H1   82730496ll
#define OFF_FIN  95313408ll     // fp32 (unused since R14)
#define OFF_IDX  107896320ll
#define OFF_VT   108158464ll    // V^T bf16 [b*6+h][64][4096]
#define OFF_FT   114449920ll    // features row-major bf16 [b*4096+n][384]
#define OFF_PO   120741376ll    // partial O bf16 [ks*12 + b*6+h][4096][64] (R17)
#define OFF_PD   145907200ll    // partial denom f32 [ks*12 + b*6+h][4096]
#define WS_NEED  146300416ull

// converted-input element offsets within CONV (u16 elements)
// (points region [0, 3170304) is DEAD since R15: ftrans reads raw input)
#define CV_LN1G 3170304ll
#define CV_LN1B 3170688ll
#define CV_AOB  3760896ll
#define CV_KNNB 4056192ll
#define CV_MRGB 4351488ll
#define CV_LN2G 4351872ll
#define CV_LN2B 4352256ll
#define CV_FF1B 4647552ll
#define CV_FF2B 4943232ll

// transposed-weight element offsets within WT (u16 elements)
#define WT_QKV 0ll
#define WT_AO  442368ll
#define WT_KNN 589824ll
#define WT_MRG 884736ll
#define WT_FF1 1179648ll
#define WT_FF2 1474560ll

static char* g_scratch = nullptr;
__attribute__((constructor)) static void athena_ws_init(void){
  void* p = nullptr;
  if (hipMalloc(&p, WS_NEED) != hipSuccess) p = nullptr;
  g_scratch = (char*)p;
}

static __device__ __forceinline__ float bf2f(u16 u){
  union { unsigned int i; float f; } x; x.i = ((unsigned int)u) << 16; return x.f;
}
static __device__ __forceinline__ u16 f2bf(float f){
  __hip_bfloat16 h = __float2bfloat16(f);
  u16 u; __builtin_memcpy(&u, &h, 2); return u;
}
// pack two f32 -> u32 of 2 bf16 (truncating): low16 = a, high16 = b
static __device__ __forceinline__ unsigned pack2(float a, float b){
  union { float f; unsigned u; } x, y; x.f = a; y.f = b;
  return (x.u >> 16) | (y.u & 0xFFFF0000u);
}
// async global->LDS, 16B per lane; lds dest = wave-uniform base + lane*16
static __device__ __forceinline__ void gload_lds16(const u16* g, u16* l){
  __builtin_amdgcn_global_load_lds(
      (const __attribute__((address_space(1))) unsigned int*)g,
      (__attribute__((address_space(3))) unsigned int*)l, 16, 0, 0);
}

// ---------------- stage0: fused convert + weight-transpose + feature-transpose -------
// All parts depend only on d_in. Block ranges:
//   [0,512)      : 6 weight matrices, raw -> bf16 (+Q-col pre-scale) -> transposed wT
//   [512,1280)   : feature transpose pts(b,3+d,n) raw -> ft[b*4096+n][384] bf16
//   [1280,1284)  : 9 small param arrays raw -> bf16 -> cv sections
//   [1284,1380)  : coords raw -> crd f32 + d_out channels 0..2
struct InPtrs { const void* p[16]; };
__global__ __launch_bounds__(256) void stage0(
    InPtrs ip, u16* __restrict__ cv, u16* __restrict__ wT,
    u16* __restrict__ ft, float* __restrict__ crd, float* __restrict__ out)
{
  __shared__ u16 tile[64*72];
  const bool isbf = (((const u16*)ip.p[1])[0] == 0x3F80);
  const int bid = blockIdx.x;
  if (bid < 512){
    const int widx[6] = {3, 4, 6, 8, 12, 14};
    const long dof[6] = {WT_QKV, WT_AO, WT_KNN, WT_MRG, WT_FF1, WT_FF2};
    const int Rt[6] = {384, 384, 768, 768, 384, 768};
    const int Ct[6] = {1152, 384, 384, 384, 768, 384};
    const int tid = bid*256 + threadIdx.x;
    const int nth = 512*256;
    for (int s = 0; s < 6; ++s){
      const void* src = ip.p[widx[s]];
      u16* outp = wT + dof[s];
      const int R = Rt[s], Cc = Ct[s], total = R*Cc;
      for (int i = tid; i < total; i += nth){
        int r = i / Cc, c = i - r*Cc;
        float f = isbf ? bf2f(((const u16*)src)[i]) : ((const float*)src)[i];
        if (s == 0 && c < 384) f *= 0.18033688f;   // Q pre-scale 1/8*log2e
        outp[(long)c*R + r] = f2bf(f);
      }
    }
  } else if (bid < 1280){
    const int t = threadIdx.x;
    int lb = bid - 512;                    // 0..767
    const int b = lb / 384; lb -= b*384;   // 384 = 64 n-tiles * 6 d-tiles
    const int d0 = (lb / 64) * 64;
    const int n0 = (lb & 63) * 64;
    {
      int dd = t >> 2, nc = (t & 3) * 16;
      const long so = (long)b*PTS_STRIDE + (long)(3+d0+dd)*4096 + n0 + nc;
      union { uint4 v[2]; u16 s[16]; } tv;
      if (isbf){
        const u16* sp = (const u16*)ip.p[0] + so;
        tv.v[0] = *(const uint4*)sp; tv.v[1] = *(const uint4*)(sp+8);
      } else {
        const float* sp = (const float*)ip.p[0] + so;
#pragma unroll
        for (int j = 0; j < 16; ++j) tv.s[j] = f2bf(sp[j]);
      }
#pragma unroll
      for (int j = 0; j < 16; ++j) tile[dd*72 + nc + j] = tv.s[j];
    }
    __syncthreads();
    {
      int nn = t >> 2, dc = (t & 3) * 16;
      union { uint4 v[2]; u16 s[16]; } tw;
#pragma unroll
      for (int j = 0; j < 16; ++j) tw.s[j] = tile[(dc+j)*72 + nn];
      u16* dst = &ft[((long)(b*4096 + n0 + nn))*384 + d0 + dc];
      *(uint4*)dst = tw.v[0]; *(uint4*)(dst+8) = tw.v[1];
    }
  } else if (bid < 1284){
    const int tid = (bid-1280)*256 + threadIdx.x;   // 0..1023
    const int nth = 4*256;
    const int pidx[9] = {1, 2, 5, 7, 9, 10, 11, 13, 15};
    const long coff[9] = {CV_LN1G, CV_LN1B, CV_AOB, CV_KNNB, CV_MRGB,
                          CV_LN2G, CV_LN2B, CV_FF1B, CV_FF2B};
    const int cnt[9] = {384, 384, 384, 384, 384, 384, 384, 768, 384};
    for (int s = 0; s < 9; ++s){
      const void* src = ip.p[pidx[s]];
      for (int i = tid; i < cnt[s]; i += nth){
        u16 v = isbf ? ((const u16*)src)[i] : f2bf(((const float*)src)[i]);
        cv[coff[s] + i] = v;
      }
    }
  } else {
    const int tid = (bid-1284)*256 + threadIdx.x;
    const int nth = 96*256;
    for (int i = tid; i < 24576; i += nth){
      int b = i / 12288, r = i % 12288;
      long off = (long)b*PTS_STRIDE + r;
      float v = isbf ? bf2f(((const u16*)ip.p[0])[off]) : ((const float*)ip.p[0])[off];
      crd[i] = v;
      out[off] = v;
    }
  }
}

// ---------------- V^T pre-transpose: qkv -> vT[(b*6+h)][d][n] ----------------
__global__ __launch_bounds__(256) void vtrans_k(
    const u16* __restrict__ qkv, u16* __restrict__ vT)
{
  __shared__ u16 tile[64*72];
  const int n0 = blockIdx.x*64, h = blockIdx.y, b = blockIdx.z;
  const int t = threadIdx.x;
  {
    int n = n0 + (t & 63), db = (t >> 6) * 16;
    const u16* src = &qkv[((long)b*4096 + n)*1152 + 768 + h*64 + db];
    union { uint4 v[2]; u16 s[16]; } tv;
    tv.v[0] = *(const uint4*)src; tv.v[1] = *(const uint4*)(src+8);
#pragma unroll
    for (int j = 0; j < 16; ++j) tile[(db+j)*72 + (t & 63)] = tv.s[j];
  }
  __syncthreads();
  {
    int d = t >> 2, nc = (t & 3) * 16;
    union { uint4 v[2]; u16 s[16]; } tv;
#pragma unroll
    for (int j = 0; j < 16; ++j) tv.s[j] = tile[d*72 + nc + j];
    u16* dst = &vT[((long)(b*6 + h)*64 + d)*4096 + n0 + nc];
    *(uint4*)dst = tv.v[0]; *(uint4*)(dst+8) = tv.v[1];
  }
}

// ---------------- LayerNorm bf16 (fp32 internal), row-major input ----------------
__global__ __launch_bounds__(256) void ln_kernel(
    const u16* __restrict__ in, const u16* __restrict__ g,
    const u16* __restrict__ bb, u16* __restrict__ out)
{
  const int w = threadIdx.x >> 6, lane = threadIdx.x & 63;
  const int row = blockIdx.x * 4 + w;
  float x[6];
#pragma unroll
  for (int i = 0; i < 6; ++i){
    int d = lane + i*64;
    x[i] = bf2f(in[(long)row*384 + d]);
  }
  float s = 0.f;
#pragma unroll
  for (int i = 0; i < 6; ++i) s += x[i];
#pragma unroll
  for (int off = 1; off < 64; off <<= 1) s += __shfl_xor(s, off);
  float mean = s * (1.f/384.f);
  float vs = 0.f;
#pragma unroll
  for (int i = 0; i < 6; ++i){ float d = x[i]-mean; vs += d*d; }
#pragma unroll
  for (int off = 1; off < 64; off <<= 1) vs += __shfl_xor(vs, off);
  float rstd = 1.f / sqrtf(vs * (1.f/384.f) + 1e-5f);
#pragma unroll
  for (int i = 0; i < 6; ++i){
    int d = lane + i*64;
    out[(long)row*384 + d] = f2bf((x[i]-mean)*rstd*bf2f(g[d]) + bf2f(bb[d]));
  }
}

// ---------------- 64x64-tile bf16 MFMA GEMM body, BK=128 (gload_lds + T2 swizzle) ----
// cf32 modes: 0 = bf16 C; 1 = fp32 C (linear); 2 = fp32 TRANSPOSED direct to
// points-layout out (fused write_out): out[b][3+col][n], float4 over n=quad*4..+3.
static __device__ __forceinline__ void gemm64_body(
    const u16* __restrict__ A, int lda,
    const u16* __restrict__ B, int ldb,
    void* C0, int ldc, int cf32,
    const u16* __restrict__ bias,
    const u16* __restrict__ resid, int ldr,
    int Kd, int act, int m0, int n0,
    u16* As, u16* Bs)
{
  const int tid = threadIdx.x;
  const int wv = tid >> 6, lane = tid & 63, quad = lane >> 4, l16 = lane & 15;
  const int wr = wv >> 1, wc = wv & 1;               // 2x2 wave grid, 32x32 each
  const int r4 = lane >> 4;                           // 0..3 row within a call
  const int sl = lane & 15;                           // 16B slot 0..15

  f32x4 acc[2][2] = { { {0,0,0,0},{0,0,0,0} }, { {0,0,0,0},{0,0,0,0} } };
  const int rsw = l16 * 8;                            // read-side XOR (row&15)*8

  for (int k0 = 0; k0 < Kd; k0 += 128){
    __syncthreads();   // all waves done reading LDS from previous step
#pragma unroll
    for (int c = 0; c < 4; ++c){
      const int rbase = wv*16 + c*4;                  // 4 rows per call
      const int rowin = rbase + r4;
      const int scol = (sl ^ (rowin & 15)) * 8;       // inverse-swizzled global col
      gload_lds16(A + (long)(m0 + rowin)*lda + k0 + scol, &As[rbase*128]);
      gload_lds16(B + (long)(n0 + rowin)*ldb + k0 + scol, &Bs[rbase*128]);
    }
    __syncthreads();   // implicit vmcnt(0) drain: tiles visible
#pragma unroll
    for (int ks2 = 0; ks2 < 4; ++ks2){
      const int rc = (ks2*32 + quad*8) ^ rsw;
      bf16x8 af[2], bfr[2];
#pragma unroll
      for (int mt = 0; mt < 2; ++mt)
        af[mt] = *(const bf16x8*)&As[(wr*32 + mt*16 + l16)*128 + rc];
#pragma unroll
      for (int nt = 0; nt < 2; ++nt)
        bfr[nt] = *(const bf16x8*)&Bs[(wc*32 + nt*16 + l16)*128 + rc];
#pragma unroll
      for (int mt = 0; mt < 2; ++mt)
#pragma unroll
        for (int nt = 0; nt < 2; ++nt)
          acc[mt][nt] = __builtin_amdgcn_mfma_f32_16x16x32_bf16(af[mt], bfr[nt], acc[mt][nt], 0, 0, 0);
    }
  }
#pragma unroll
  for (int nt = 0; nt < 2; ++nt){
    const int col = n0 + wc*32 + nt*16 + l16;
    const float bv = bias ? bf2f(bias[col]) : 0.f;
#pragma unroll
    for (int mt = 0; mt < 2; ++mt){
      if (cf32 == 2){
        // fused transposed store to points layout: row = b*4096+n, col = d
        const int row = m0 + wr*32 + mt*16 + quad*4;   // n base (r = 0..3 consecutive)
        f32x4 vv;
#pragma unroll
        for (int r = 0; r < 4; ++r){
          float v = acc[mt][nt][r] + bv;
          if (resid) v += bf2f(resid[(long)(row + r)*ldr + col]);
          vv[r] = v;
        }
        const long off = (long)(row >> 12)*PTS_STRIDE + (long)(3 + col)*4096 + (row & 4095);
        *(f32x4*)&((float*)C0)[off] = vv;
      } else {
#pragma unroll
        for (int r = 0; r < 4; ++r){
          const int row = m0 + wr*32 + mt*16 + quad*4 + r;  // C/D: row=quad*4+r, col=l16
          float v = acc[mt][nt][r] + bv;
          if (act == 1) v = 0.5f * v * (1.f + erff(v * 0.70710678f));
          if (resid) v += bf2f(resid[(long)row*ldr + col]);
          if (cf32) ((float*)C0)[(long)row*ldc + col] = v;
          else      ((u16*)C0)[(long)row*ldc + col] = f2bf(v);
        }
      }
    }
  }
}

// ---------------- Unified GEMM (64x64 tile, BK=128) ----------------
__global__ __launch_bounds__(256) void gemm_k(
    const u16* __restrict__ A, int lda,
    const u16* __restrict__ B, int ldb,
    void* C0, int ldc, int cf32,
    const u16* __restrict__ bias,
    const u16* __restrict__ resid, int ldr,
    int Kd, int act)
{
  __shared__ u16 As[64*128];
  __shared__ u16 Bs[64*128];
  gemm64_body(A, lda, B, ldb, C0, ldc, cf32, bias, resid, ldr, Kd, act,
              blockIdx.y*64, blockIdx.x*64, As, Bs);
}

// ---------------- grouped GEMM: 3 independent M=8192,N=384,K=384 GEMMs --------------
__global__ __launch_bounds__(256) void gemm3_k(
    const u16* __restrict__ aop, const u16* __restrict__ nf,
    const u16* __restrict__ wTao, const u16* __restrict__ wTknn,
    u16* __restrict__ cat1, u16* __restrict__ A1, u16* __restrict__ A2,
    const u16* __restrict__ aob, const u16* __restrict__ knnb)
{
  __shared__ u16 As[64*128];
  __shared__ u16 Bs[64*128];
  const int z = blockIdx.z;
  const u16* A  = (z == 0) ? aop : nf;
  const u16* B  = (z == 0) ? wTao : (z == 1 ? wTknn : wTknn + 384);
  const int ldb = (z == 0) ? 384 : 768;
  u16* C        = (z == 0) ? cat1 : (z == 1 ? A1 : A2);
  const int ldc = (z == 0) ? 768 : 384;
  const u16* bias = (z == 0) ? aob : (z == 2 ? knnb : nullptr);
  gemm64_body(A, 384, B, ldb, C, ldc, 0, bias, nullptr, 0, 384, 0,
              blockIdx.y*64, blockIdx.x*64, As, Bs);
}

// ---------------- Flash attention v9: 32x32 MFMA, P in-register, K-SPLIT ------------
// grid = (N/128, H, B*2) = 768 blocks (3/CU exact, 12 waves/CU, 3 waves/SIMD).
// blockIdx.z = b*2 + ksplit; each block processes 32 of 64 k-tiles and writes
// UNNORMALIZED partial O (bf16, R17: halves the partials round-trip traffic)
// + partial denominator (f32); attn_combine merges.
// Softmax via raw v_exp_f32 (__builtin_amdgcn_exp2f).
__global__ __launch_bounds__(256) void flash_attn(
    const u16* __restrict__ qkv, const u16* __restrict__ vT,
    u16* __restrict__ po, float* __restrict__ pd)
{
  __shared__ u16 ks_[2][64*72];   // K tile [k][d]
  __shared__ u16 vs_[2][64*72];   // V^T tile [d][k]
  const int tid = threadIdx.x;
  const int w = tid >> 6, lane = tid & 63;
  const int l31 = lane & 31, hi = lane >> 5;
  const int q0 = blockIdx.x * 128, h = blockIdx.y;
  const int b = blockIdx.z & 1, ks0 = blockIdx.z >> 1;
  const int t0 = ks0 * 32;        // first k-tile of this split
  const long base = (long)b * 4096 * 1152;
  const u16* vrow = vT + (long)(b*6 + h)*262144;

  // Q fragments (B-operand): lane holds q-col = q0+w*32+l31; d = dm*16 + hi*8 + j
  bf16x8 qf[4];
  {
    const long qoff = base + (long)(q0 + w*32 + l31)*1152 + h*64 + hi*8;
#pragma unroll
    for (int dm = 0; dm < 4; ++dm)
      qf[dm] = *(const bf16x8*)&qkv[qoff + dm*16];
  }
  bf16x8 ones;
#pragma unroll
  for (int i = 0; i < 8; ++i) ones[i] = (__bf16)1.0f;

  f32x16 o0 = {}, o1 = {}, dn = {};

  // cooperative staging: rows sr = tid>>2 (0..63), cols sk = (tid&3)*16, 2x uint4 each
  const int sr = tid >> 2, sk = (tid & 3) * 16;
  const u16* kg = qkv + base + 384 + h*64 + (long)sr*1152 + sk;
  const u16* vg = vrow + (long)sr*4096 + sk;

  // prologue: stage tile t0 into buffer 0
  {
    const u16* kg0 = kg + (long)t0*64*1152;
    const u16* vg0 = vg + t0*64;
    uint4 k0 = *(const uint4*)kg0,  k1 = *(const uint4*)(kg0+8);
    uint4 v0 = *(const uint4*)vg0,  v1 = *(const uint4*)(vg0+8);
    *(uint4*)&ks_[0][sr*72+sk] = k0;  *(uint4*)&ks_[0][sr*72+sk+8] = k1;
    *(uint4*)&vs_[0][sr*72+sk] = v0;  *(uint4*)&vs_[0][sr*72+sk+8] = v1;
  }

  for (int kt = 0; kt < 32; ++kt){
    const int cur = kt & 1;
    uint4 k0, k1, v0, v1;
    const bool pre = (kt < 31);
    if (pre){
      const u16* kgn = kg + (long)(t0 + kt + 1)*64*1152;
      const u16* vgn = vg + (t0 + kt + 1)*64;
      k0 = *(const uint4*)kgn; k1 = *(const uint4*)(kgn+8);
      v0 = *(const uint4*)vgn; v1 = *(const uint4*)(vgn+8);
    }
    __syncthreads();   // staged[cur] visible; prev iter's reads of buf[cur^1] done

    // QK^T: two 32x32 S^T tiles (k-halves). z[r] = S[q=l31][k = (r&3)+8*(r>>2)+4*hi]
    bf16x8 pa[4];
#pragma unroll
    for (int t = 0; t < 2; ++t){
      f32x16 z = {};
#pragma unroll
      for (int dm = 0; dm < 4; ++dm){
        bf16x8 kf = *(const bf16x8*)&ks_[cur][(t*32 + l31)*72 + dm*16 + hi*8];
        z = __builtin_amdgcn_mfma_f32_32x32x16_bf16(kf, qf[dm], z, 0, 0, 0);
      }
      float p[16];
#pragma unroll
      for (int r = 0; r < 16; ++r) p[r] = __builtin_amdgcn_exp2f(z[r]);
      // build PV A-fragments for the two 16-k subtiles of this tile:
      // frag word j covers k = {2j,2j+1} (lanes hi=0) / {8+2j,8+2j+1} (hi=1).
      // permlane32_swap(vdst,vsrc): vdst.hi-lanes <-> vsrc.lo-lanes.
#pragma unroll
      for (int s = 0; s < 2; ++s){
        const float* pp = p + s*8;
        unsigned a0 = pack2(pp[0], pp[1]);   // k{0,1}+4hi (local)
        unsigned a1 = pack2(pp[4], pp[5]);   // k{8,9}+4hi
        unsigned b0 = pack2(pp[2], pp[3]);   // k{2,3}+4hi
        unsigned b1 = pack2(pp[6], pp[7]);   // k{10,11}+4hi
        i32x2 rA = __builtin_amdgcn_permlane32_swap((int)a0, (int)a1, false, false);
        i32x2 rB = __builtin_amdgcn_permlane32_swap((int)b0, (int)b1, false, false);
        union { unsigned u[4]; bf16x8 v; } fr;
        fr.u[0] = (unsigned)rA[0];   // k{0,1}/{8,9}
        fr.u[1] = (unsigned)rB[0];   // k{2,3}/{10,11}
        fr.u[2] = (unsigned)rA[1];   // k{4,5}/{12,13}
        fr.u[3] = (unsigned)rB[1];   // k{6,7}/{14,15}
        pa[t*2 + s] = fr.v;
      }
    }

    // write next tile into the other buffer (its readers are past next barrier)
    if (pre){
      *(uint4*)&ks_[cur^1][sr*72+sk] = k0;  *(uint4*)&ks_[cur^1][sr*72+sk+8] = k1;
      *(uint4*)&vs_[cur^1][sr*72+sk] = v0;  *(uint4*)&vs_[cur^1][sr*72+sk+8] = v1;
    }

    // PV + denominator, all on the MFMA pipe. vf: lane col d = dsub*32+l31, k = ks*16+hi*8+j
#pragma unroll
    for (int ks = 0; ks < 4; ++ks){
      bf16x8 vf0 = *(const bf16x8*)&vs_[cur][(l31)*72      + ks*16 + hi*8];
      bf16x8 vf1 = *(const bf16x8*)&vs_[cur][(32 + l31)*72 + ks*16 + hi*8];
      o0 = __builtin_amdgcn_mfma_f32_32x32x16_bf16(pa[ks], vf0, o0, 0, 0, 0);
      o1 = __builtin_amdgcn_mfma_f32_32x32x16_bf16(pa[ks], vf1, o1, 0, 0, 0);
      dn = __builtin_amdgcn_mfma_f32_32x32x16_bf16(pa[ks], ones, dn, 0, 0, 0);
    }
  }

  // write UNNORMALIZED bf16 partials. C/D rows: q = (r&3)+8*(r>>2)+4*hi; d = dsub*32+l31.
  const long slab = (long)(ks0*12 + b*6 + h) * 4096;
#pragma unroll
  for (int r = 0; r < 16; ++r){
    const int q = (r & 3) + 8*(r >> 2) + 4*hi;
    const long qi = slab + q0 + w*32 + q;
    po[qi*64 + l31]      = f2bf(o0[r]);
    po[qi*64 + 32 + l31] = f2bf(o1[r]);
    if (l31 == 0) pd[qi] = dn[r];
  }
}

// ---------------- combine the two K-split halves -> aop bf16 ----------------
// idx = ((b*6+h)*4096 + q)*16 + d4 ; each thread merges 4 consecutive d.
__global__ __launch_bounds__(256) void attn_combine(
    const u16* __restrict__ po, const float* __restrict__ pd,
    u16* __restrict__ aop)
{
  const int idx = blockIdx.x*256 + threadIdx.x;   // < 786432
  const int d4 = idx & 15;
  const int q  = (idx >> 4) & 4095;
  const int bh = idx >> 16;                        // 0..11
  const long r0 = (long)bh*4096 + q;
  const long r1 = (long)(12 + bh)*4096 + q;
  const float inv = 1.f / (pd[r0] + pd[r1]);
  ushort4 a4 = *(const ushort4*)&po[r0*64 + d4*4];
  ushort4 c4 = *(const ushort4*)&po[r1*64 + d4*4];
  const int b = bh / 6, h = bh - 6*b;
  ushort4 w4;
  w4.x = f2bf((bf2f(a4.x) + bf2f(c4.x)) * inv);
  w4.y = f2bf((bf2f(a4.y) + bf2f(c4.y)) * inv);
  w4.z = f2bf((bf2f(a4.z) + bf2f(c4.z)) * inv);
  w4.w = f2bf((bf2f(a4.w) + bf2f(c4.w)) * inv);
  *(ushort4*)&aop[((long)(b*4096 + q))*384 + h*64 + d4*4] = w4;
}

// ---------------- KNN top-8 v3: chunked LDS staging, 2 rows/wave ----------------
// grid = 1024 blocks x 256 threads; block handles 8 consecutive rows (same batch).
// Candidates processed in 2 chunks of 2048 (LDS 24 KB); query top-8 state in
// registers across chunks. Per-lane insert strict-< only (exact, R12-verified);
// cross-lane merge keeps (dist,idx) tie-break.
__global__ __launch_bounds__(256) void knn_topk(
    const float* __restrict__ crd, int* __restrict__ idxout)
{
  __shared__ float cs[6144];   // [3][2048] per chunk
  const int w = threadIdx.x >> 6, lane = threadIdx.x & 63;
  const int rb = blockIdx.x * 8;
  const int b = rb >> 12;                 // 4096 % 8 == 0: whole block same batch
  const long pb = (long)b * 12288;

  const int rw = rb + w*2;
  float xn[2], yn[2], zn[2], sqn[2];
#pragma unroll
  for (int q = 0; q < 2; ++q){
    const int n = (rw + q) & 4095;
    xn[q] = crd[pb + n]; yn[q] = crd[pb + 4096 + n]; zn[q] = crd[pb + 8192 + n];
    sqn[q] = __fadd_rn(__fadd_rn(__fmul_rn(xn[q],xn[q]), __fmul_rn(yn[q],yn[q])),
                       __fmul_rn(zn[q],zn[q]));
  }

  float bd[2][8]; int bi[2][8];
#pragma unroll
  for (int q = 0; q < 2; ++q)
#pragma unroll
    for (int j = 0; j < 8; ++j){ bd[q][j] = 3.4e38f; bi[q][j] = 0x7fffffff; }

  for (int c0 = 0; c0 < 4096; c0 += 2048){
    __syncthreads();   // previous chunk's reads complete before overwrite
    for (int i = threadIdx.x; i < 1536; i += 256){
      const int s = i >> 9, e = (i & 511) * 4;
      float4 v4 = *(const float4*)&crd[pb + (long)s*4096 + c0 + e];
      *(float4*)&cs[s*2048 + e] = v4;
    }
    __syncthreads();

    for (int m0 = 0; m0 < 2048; m0 += 64){
      const int ml = m0 + lane;
      const int m = c0 + ml;
      const float xm = cs[ml], ym = cs[2048 + ml], zm = cs[4096 + ml];
      const float sqm = __fadd_rn(__fadd_rn(__fmul_rn(xm,xm), __fmul_rn(ym,ym)),
                                  __fmul_rn(zm,zm));
#pragma unroll
      for (int q = 0; q < 2; ++q){
        const float dot = __fadd_rn(__fadd_rn(__fmul_rn(xn[q],xm), __fmul_rn(yn[q],ym)),
                                    __fmul_rn(zn[q],zm));
        float v = __fadd_rn(__fadd_rn(sqn[q], sqm), __fmul_rn(-2.f, dot));
        int vi = m;
        if (v < bd[q][7]){
#pragma unroll
          for (int j = 0; j < 8; ++j){
            bool c = v < bd[q][j];
            float td = bd[q][j]; int ti = bi[q][j];
            bd[q][j] = c ? v : td;  bi[q][j] = c ? vi : ti;
            v = c ? td : v;         vi = c ? ti : vi;
          }
        }
      }
    }
  }
#pragma unroll
  for (int q = 0; q < 2; ++q){
    const int row = rw + q;
    for (int t = 0; t < 8; ++t){
      float rd = bd[q][0]; int ri = bi[q][0]; int rl = lane;
#pragma unroll
      for (int off = 1; off < 64; off <<= 1){
        float od = __shfl_xor(rd, off); int oi = __shfl_xor(ri, off); int ol = __shfl_xor(rl, off);
        bool take = (od < rd) || (od == rd && oi < ri);
        rd = take ? od : rd; ri = take ? oi : ri; rl = take ? ol : rl;
      }
      if (lane == 0) idxout[row*8 + t] = ri;
      if (lane == rl){
#pragma unroll
        for (int j = 0; j < 7; ++j){ bd[q][j] = bd[q][j+1]; bi[q][j] = bi[q][j+1]; }
        bd[q][7] = 3.4e38f; bi[q][7] = 0x7fffffff;
      }
    }
  }
}

// ---------------- gather-max (bf16) -> cat1 cols 384..767 ----------------
__global__ __launch_bounds__(384) void knn_gather_max(
    const u16* __restrict__ A1, const u16* __restrict__ A2,
    const int* __restrict__ idx, u16* __restrict__ cat1)
{
  const int row = blockIdx.x;
  const int d = threadIdx.x;
  const int b = row >> 12;
  const float bs = bf2f(A2[(long)row*384 + d]) - bf2f(A1[(long)row*384 + d]);
  float mx = -3.4e38f;
#pragma unroll
  for (int k = 0; k < 8; ++k){
    int r = idx[row*8 + k] & 4095;
    float v = bf2f(A1[(long)(b*4096 + r)*384 + d]) + bs;
    v = (v > 0.f) ? v : 0.2f*v;
    mx = fmaxf(mx, v);
  }
  cat1[(long)row*768 + 384 + d] = f2bf(mx);
}

extern "C" void kernel_launch(void* const* d_in, const int* in_sizes, int n_in,
                              void* d_out, int out_size, void* d_ws, size_t ws_size,
                              hipStream_t stream) {
  (void)in_sizes; (void)n_in; (void)out_size; (void)ws_size; (void)d_ws;
  float* out = (float*)d_out;          // output dtype = float32 (verified R9)
  char* ws = g_scratch;

  u16*   cv   = (u16*)(ws + OFF_CONV);
  float* crd  = (float*)(ws + OFF_CRDF);
  u16*   wT   = (u16*)(ws + OFF_WT);
  u16*   nf   = (u16*)(ws + OFF_NF);
  u16*   qkv  = (u16*)(ws + OFF_QKV);
  u16*   aop  = (u16*)(ws + OFF_AOP);
  u16*   cat1 = (u16*)(ws + OFF_CAT1);
  u16*   A1b  = (u16*)(ws + OFF_A1);
  u16*   A2b  = (u16*)(ws + OFF_A2);
  u16*   out1 = (u16*)(ws + OFF_OUT1);
  u16*   out2 = (u16*)(ws + OFF_OUT2);
  u16*   h1   = (u16*)(ws + OFF_H1);
  int*   idxb = (int*)(ws + OFF_IDX);
  u16*   vTb  = (u16*)(ws + OFF_VT);
  u16*   ft   = (u16*)(ws + OFF_FT);
  u16*   pob  = (u16*)(ws + OFF_PO);
  float* pdb  = (float*)(ws + OFF_PD);

  const u16 *c_ln1g = cv+CV_LN1G, *c_ln1b = cv+CV_LN1B,
            *c_aob = cv+CV_AOB, *c_knnb = cv+CV_KNNB, *c_mrgb = cv+CV_MRGB,
            *c_ln2g = cv+CV_LN2G, *c_ln2b = cv+CV_LN2B, *c_ff1b = cv+CV_FF1B,
            *c_ff2b = cv+CV_FF2B;
  u16 *wTq = wT+WT_QKV, *wTao = wT+WT_AO, *wTknn = wT+WT_KNN,
      *wTmrg = wT+WT_MRG, *wTff1 = wT+WT_FF1, *wTff2 = wT+WT_FF2;

  // 0. fused stage0: weights transpose + feature transpose + params + coords
  InPtrs ip; for (int i = 0; i < 16; ++i) ip.p[i] = d_in[i];
  stage0<<<1380, 256, 0, stream>>>(ip, cv, wT, ft, crd, out);

  // 1. LN1 (coalesced row-major) -> nf
  ln_kernel<<<2048, 256, 0, stream>>>(ft, c_ln1g, c_ln1b, nf);
  // 2. qkv = nf @ qkv_w   (Q columns pre-scaled by 1/8*log2e in wTq)
  gemm_k<<<dim3(18,128), 256, 0, stream>>>(nf, 384, wTq, 384,
      qkv, 1152, 0, nullptr, nullptr, 0, 384, 0);
  // 2b. V^T pre-transpose
  vtrans_k<<<dim3(64,6,2), 256, 0, stream>>>(qkv, vTb);
  // 3. flash attention v9 (K-split, bf16 partials) -> combine -> aop
  flash_attn<<<dim3(32,6,4), 256, 0, stream>>>(qkv, vTb, pob, pdb);
  attn_combine<<<3072, 256, 0, stream>>>(pob, pdb, aop);
  // 4+6. grouped: attn-out GEMM, A1, A2
  gemm3_k<<<dim3(6,128,3), 256, 0, stream>>>(aop, nf, wTao, wTknn,
      cat1, A1b, A2b, c_aob, c_knnb);
  // 5. top-8 neighbors (chunked LDS, 2 rows/wave)
  knn_topk<<<1024, 256, 0, stream>>>(crd, idxb);
  // 7. geom -> cat1 cols 384..767
  knn_gather_max<<<8192, 384, 0, stream>>>(A1b, A2b, idxb, cat1);
  // 8. out1 = cat1 @ merge_w + merge_b + attn(resid = cat1 cols 0..383)
  gemm_k<<<dim3(6,128), 256, 0, stream>>>(cat1, 768, wTmrg, 768,
      out1, 384, 0, c_mrgb, cat1, 768, 768, 0);
  // 9. LN2
  ln_kernel<<<2048, 256, 0, stream>>>(out1, c_ln2g, c_ln2b, out2);
  // 10. h1 = gelu(out2 @ ff1_w + ff1_b)
  gemm_k<<<dim3(12,128), 256, 0, stream>>>(out2, 384, wTff1, 384,
      h1, 768, 0, c_ff1b, nullptr, 0, 384, 1);
  // 11. out[3+d][n] = (h1 @ ff2_w + ff2_b + out2)^T  -- fused write_out (cf32=2)
  gemm_k<<<dim3(6,128), 256, 0, stream>>>(h1, 768, wTff2, 768,
      out, 0, 2, c_ff2b, out2, 384, 768, 0);
}